// Round 8
// baseline (210.299 us; speedup 1.0000x reference)
//
#include <hip/hip_runtime.h>
#include <math.h>

#define BD 8
#define NN 1000
#define GG 1000
#define EE 128

typedef unsigned long long u64;
typedef __attribute__((ext_vector_type(8))) short short8;   // 8 bf16 (4 VGPRs)
typedef __attribute__((ext_vector_type(4))) float f32x4;

// ws layout (floats)
#define OFF_QG    0                       // B*128
#define OFF_K     1024                    // 8000*128
#define OFF_V     (OFF_K + 1024000)
#define OFF_QFL   (OFF_V + 1024000)
#define OFF_OUTG  (OFF_QFL + 1024000)
#define OFF_FQ    (OFF_OUTG + 1024000)
#define OFF_PART  (OFF_FQ + 1024000)      // 8000*8
#define OFF_GPART (OFF_PART + 64000)      // 8*25*128
// After k_glimpse, Karr/Varr are dead -> emb3 frag buffer aliases OFF_K (needs 1.573M float slots < 2.048M)
// After k_comb, QFL/outg are dead -> fq3 frag buffer aliases OFF_QFL (same size; ends before OFF_FQ)

// ---------------- K1a: partial row sums of embeddings (B x 25 x 128) ----------------
__global__ __launch_bounds__(256) void k_gq1(const float* __restrict__ emb,
                                             float* __restrict__ gpart) {
  __shared__ float ps[2][128];
  int b = blockIdx.x, blk = blockIdx.y;
  int t = threadIdx.x;
  int e = t & 127, p = t >> 7;  // 2 half-slices of 20 rows
  const float* eb = emb + ((size_t)b * NN + blk * 40 + p * 20) * EE + e;
  float s = 0.f;
#pragma unroll 4
  for (int n = 0; n < 20; ++n) s += eb[(size_t)n * EE];
  ps[p][e] = s;
  __syncthreads();
  if (t < 128) gpart[(b * 25 + blk) * 128 + t] = ps[0][t] + ps[1][t];
}

// ---------------- K1b: finalize mean + q_graph = mean @ Wqg^T ----------------
__global__ __launch_bounds__(128) void k_gq2(const float* __restrict__ gpart,
                                             const float* __restrict__ Wqg,
                                             float* __restrict__ qg) {
  __shared__ float ge[128];
  int b = blockIdx.x, t = threadIdx.x;
  float s = 0.f;
#pragma unroll 5
  for (int j = 0; j < 25; ++j) s += gpart[(b * 25 + j) * 128 + t];
  ge[t] = s * (1.f / 1000.f);
  __syncthreads();
  const float* wr = Wqg + (size_t)t * EE;
  float acc = 0.f;
#pragma unroll 8
  for (int k = 0; k < 128; ++k) acc += ge[k] * wr[k];
  qg[b * EE + t] = acc;
}

// ---------------- K2: fused projection GEMM  P = emb @ [Wk;Wv;Wqf+Wql]^T ----------------
// grid (125, 6), block 256. Tile 64x64, thread 4x4, K=128 in steps of 16.
__global__ __launch_bounds__(256) void k_proj(const float* __restrict__ emb,
                                              const float* __restrict__ Wk,
                                              const float* __restrict__ Wv,
                                              const float* __restrict__ Wqf,
                                              const float* __restrict__ Wql,
                                              float* __restrict__ Karr,
                                              float* __restrict__ Varr,
                                              float* __restrict__ QFL) {
  __shared__ float Als[16][68];
  __shared__ float Bls[16][68];
  int mt = blockIdx.x, nt = blockIdx.y;
  int t = threadIdx.x;
  int ty = t >> 4, tx = t & 15;
  int row4 = t >> 2, kq = t & 3;
  float acc[4][4] = {};
  for (int k0 = 0; k0 < 128; k0 += 16) {
    const float* ap = emb + (size_t)(mt * 64 + row4) * EE + k0 + kq * 4;
    float4 av = *(const float4*)ap;
    int j = nt * 64 + row4;
    float4 bv;
    if (j < 128) {
      bv = *(const float4*)(Wk + (size_t)j * EE + k0 + kq * 4);
    } else if (j < 256) {
      bv = *(const float4*)(Wv + (size_t)(j - 128) * EE + k0 + kq * 4);
    } else {
      float4 f = *(const float4*)(Wqf + (size_t)(j - 256) * EE + k0 + kq * 4);
      float4 l = *(const float4*)(Wql + (size_t)(j - 256) * EE + k0 + kq * 4);
      bv = make_float4(f.x + l.x, f.y + l.y, f.z + l.z, f.w + l.w);
    }
    Als[kq * 4 + 0][row4] = av.x; Als[kq * 4 + 1][row4] = av.y;
    Als[kq * 4 + 2][row4] = av.z; Als[kq * 4 + 3][row4] = av.w;
    Bls[kq * 4 + 0][row4] = bv.x; Bls[kq * 4 + 1][row4] = bv.y;
    Bls[kq * 4 + 2][row4] = bv.z; Bls[kq * 4 + 3][row4] = bv.w;
    __syncthreads();
#pragma unroll
    for (int k = 0; k < 16; ++k) {
      float a0 = Als[k][ty * 4 + 0], a1 = Als[k][ty * 4 + 1];
      float a2 = Als[k][ty * 4 + 2], a3 = Als[k][ty * 4 + 3];
      float b0 = Bls[k][tx * 4 + 0], b1 = Bls[k][tx * 4 + 1];
      float b2 = Bls[k][tx * 4 + 2], b3 = Bls[k][tx * 4 + 3];
      acc[0][0] += a0 * b0; acc[0][1] += a0 * b1; acc[0][2] += a0 * b2; acc[0][3] += a0 * b3;
      acc[1][0] += a1 * b0; acc[1][1] += a1 * b1; acc[1][2] += a1 * b2; acc[1][3] += a1 * b3;
      acc[2][0] += a2 * b0; acc[2][1] += a2 * b1; acc[2][2] += a2 * b2; acc[2][3] += a2 * b3;
      acc[3][0] += a3 * b0; acc[3][1] += a3 * b1; acc[3][2] += a3 * b2; acc[3][3] += a3 * b3;
    }
    __syncthreads();
  }
  float* outp; int cb;
  if (nt < 2)      { outp = Karr; cb = nt * 64; }
  else if (nt < 4) { outp = Varr; cb = (nt - 2) * 64; }
  else             { outp = QFL;  cb = (nt - 4) * 64; }
#pragma unroll
  for (int i = 0; i < 4; ++i) {
    int r = mt * 64 + ty * 4 + i;
    float4 v = make_float4(acc[i][0], acc[i][1], acc[i][2], acc[i][3]);
    *(float4*)(outp + (size_t)r * EE + cb + tx * 4) = v;
  }
}

// ----- u32 wave-min helpers (DPP row rotations + shfl for 16/32) -----
template <int CTRL>
__device__ __forceinline__ unsigned dpp_minu(unsigned x) {
  unsigned o = (unsigned)__builtin_amdgcn_update_dpp(0, (int)x, CTRL, 0xf, 0xf, false);
  return o < x ? o : x;
}
__device__ __forceinline__ unsigned wave_min_u32(unsigned x) {
  x = dpp_minu<0x121>(x);   // row_ror:1
  x = dpp_minu<0x122>(x);   // row_ror:2
  x = dpp_minu<0x124>(x);   // row_ror:4
  x = dpp_minu<0x128>(x);   // row_ror:8 -> 16-lane row reduced
  unsigned o = (unsigned)__shfl_xor((int)x, 16); x = o < x ? o : x;
  o = (unsigned)__shfl_xor((int)x, 32); x = o < x ? o : x;
  return x;
}

// ---------------- K3: per-(b,g) KNN + glimpse attention -> outg (B,G,128) ----------------
// one wave per (b,g); grid 2000 x 256 (4 waves/block)
__global__ __launch_bounds__(256) void k_glimpse(const int* __restrict__ last_node,
                                                 const float* __restrict__ coords,
                                                 const float* __restrict__ mask,
                                                 const float* __restrict__ qg,
                                                 const float* __restrict__ QFL,
                                                 const float* __restrict__ Karr,
                                                 const float* __restrict__ Varr,
                                                 float* __restrict__ outg) {
  __shared__ float pbuf[4][128];
  __shared__ int   nbuf[4][16];
  const float INF = __builtin_inff();
  int wv = threadIdx.x >> 6;
  int lane = threadIdx.x & 63;
  int wid = (blockIdx.x * blockDim.x + threadIdx.x) >> 6;
  int b = wid / GG, g = wid % GG;
  int last = last_node[b * GG + g];
  const float2* cb2 = (const float2*)(coords + (size_t)b * NN * 2);
  float2 lc = cb2[last];
  float lc2 = lc.x * lc.x + lc.y * lc.y;
  const float* mrow = mask + ((size_t)b * GG + g) * NN;
  unsigned d2u[16];
#pragma unroll
  for (int i = 0; i < 16; ++i) {
    int n = lane + (i << 6);
    unsigned k = 0xFFFFFFFFu;
    if (n < NN) {
      float2 c = cb2[n];
      float d2 = lc2 + (c.x * c.x + c.y * c.y) - 2.f * (lc.x * c.x + lc.y * c.y);
      d2 = fmaxf(d2, 0.f);
      k = __float_as_uint(d2);
      if (mrow[n] == -INF) k = 0x7F800000u;
    }
    d2u[i] = k;
  }
  int h = lane >> 3;   // head 0..7
  int kk = lane & 7;   // this lane scores k=kk and k=kk+8
  int n0sel = 0, n1sel = 0;
  for (int s = 0; s < 16; ++s) {
    unsigned bv = d2u[0]; int bs = 0;
#pragma unroll
    for (int i = 1; i < 16; ++i) {
      bool better = d2u[i] < bv;
      bv = better ? d2u[i] : bv;
      bs = better ? i : bs;
    }
    unsigned wm = wave_min_u32(bv);
    u64 tied = __ballot(bv == wm);
    int wn;
    if (__popcll(tied) == 1) {
      int wl = (int)__builtin_ctzll(tied);
      int ws = __builtin_amdgcn_readlane(bs, wl);
      wn = wl + (ws << 6);
    } else {
      unsigned cn = (bv == wm) ? (unsigned)(lane + (bs << 6)) : 0x7FFFFFFFu;
      cn = wave_min_u32(cn);
      wn = (int)__builtin_amdgcn_readfirstlane((int)cn);
    }
    n0sel = (s == kk) ? wn : n0sel;
    n1sel = (s == kk + 8) ? wn : n1sel;
    int iw = wn >> 6;
    bool me = (lane == (wn & 63));
#pragma unroll
    for (int i = 0; i < 16; ++i)
      if (i == iw && me) d2u[i] = 0xFFFFFFFFu;
  }
  float qh[16];
  {
    const float4* qg4 = (const float4*)(qg + b * EE + h * 16);
    const float4* qf4 = (const float4*)(QFL + ((size_t)b * NN + last) * EE + h * 16);
#pragma unroll
    for (int u = 0; u < 4; ++u) {
      float4 a = qg4[u], c = qf4[u];
      qh[u * 4 + 0] = a.x + c.x; qh[u * 4 + 1] = a.y + c.y;
      qh[u * 4 + 2] = a.z + c.z; qh[u * 4 + 3] = a.w + c.w;
    }
  }
  const float* Kb = Karr + (size_t)b * NN * EE;
  float s0 = 0.f, s1 = 0.f;
  {
    const float4* k04 = (const float4*)(Kb + (size_t)n0sel * EE + h * 16);
    const float4* k14 = (const float4*)(Kb + (size_t)n1sel * EE + h * 16);
    float4 ka[4], kb[4];
#pragma unroll
    for (int u = 0; u < 4; ++u) { ka[u] = k04[u]; kb[u] = k14[u]; }
#pragma unroll
    for (int u = 0; u < 4; ++u) {
      s0 += qh[u * 4 + 0] * ka[u].x; s0 += qh[u * 4 + 1] * ka[u].y;
      s0 += qh[u * 4 + 2] * ka[u].z; s0 += qh[u * 4 + 3] * ka[u].w;
      s1 += qh[u * 4 + 0] * kb[u].x; s1 += qh[u * 4 + 1] * kb[u].y;
      s1 += qh[u * 4 + 2] * kb[u].z; s1 += qh[u * 4 + 3] * kb[u].w;
    }
  }
  s0 *= 0.25f; s1 *= 0.25f;
  float m = fmaxf(s0, s1);
#pragma unroll
  for (int off = 1; off < 8; off <<= 1) m = fmaxf(m, __shfl_xor(m, off));
  float e0 = __expf(s0 - m), e1 = __expf(s1 - m);
  float se = e0 + e1;
#pragma unroll
  for (int off = 1; off < 8; off <<= 1) se += __shfl_xor(se, off);
  float p0 = e0 / se, p1 = e1 / se;
  pbuf[wv][h * 16 + kk] = p0;
  pbuf[wv][h * 16 + kk + 8] = p1;
  if (h == 0) { nbuf[wv][kk] = n0sel; nbuf[wv][kk + 8] = n1sel; }
  const float* Vb = Varr + (size_t)b * NN * EE;
  float o0 = 0.f, o1 = 0.f;
#pragma unroll
  for (int c = 0; c < 2; ++c) {
    int nk[8]; float pk[8]; float2 vv[8];
#pragma unroll
    for (int j = 0; j < 8; ++j) { nk[j] = nbuf[wv][c * 8 + j]; pk[j] = pbuf[wv][h * 16 + c * 8 + j]; }
#pragma unroll
    for (int j = 0; j < 8; ++j)
      vv[j] = *(const float2*)(Vb + (size_t)nk[j] * EE + h * 16 + kk * 2);
#pragma unroll
    for (int j = 0; j < 8; ++j) { o0 += pk[j] * vv[j].x; o1 += pk[j] * vv[j].y; }
  }
  *(float2*)(outg + ((size_t)b * GG + g) * EE + h * 16 + kk * 2) = make_float2(o0, o1);
}

// ---------------- K4: final_q = outg @ W_comb^T + b_comb ----------------
// grid (125, 2), block 256
__global__ __launch_bounds__(256) void k_comb(const float* __restrict__ outg,
                                              const float* __restrict__ Wc,
                                              const float* __restrict__ bc,
                                              float* __restrict__ fq) {
  __shared__ float Als[16][68];
  __shared__ float Bls[16][68];
  int mt = blockIdx.x, nt = blockIdx.y;
  int t = threadIdx.x;
  int ty = t >> 4, tx = t & 15;
  int row4 = t >> 2, kq = t & 3;
  float acc[4][4] = {};
  for (int k0 = 0; k0 < 128; k0 += 16) {
    float4 av = *(const float4*)(outg + (size_t)(mt * 64 + row4) * EE + k0 + kq * 4);
    int j = nt * 64 + row4;
    float4 bv = *(const float4*)(Wc + (size_t)j * EE + k0 + kq * 4);
    Als[kq * 4 + 0][row4] = av.x; Als[kq * 4 + 1][row4] = av.y;
    Als[kq * 4 + 2][row4] = av.z; Als[kq * 4 + 3][row4] = av.w;
    Bls[kq * 4 + 0][row4] = bv.x; Bls[kq * 4 + 1][row4] = bv.y;
    Bls[kq * 4 + 2][row4] = bv.z; Bls[kq * 4 + 3][row4] = bv.w;
    __syncthreads();
#pragma unroll
    for (int k = 0; k < 16; ++k) {
      float a0 = Als[k][ty * 4 + 0], a1 = Als[k][ty * 4 + 1];
      float a2 = Als[k][ty * 4 + 2], a3 = Als[k][ty * 4 + 3];
      float b0 = Bls[k][tx * 4 + 0], b1 = Bls[k][tx * 4 + 1];
      float b2 = Bls[k][tx * 4 + 2], b3 = Bls[k][tx * 4 + 3];
      acc[0][0] += a0 * b0; acc[0][1] += a0 * b1; acc[0][2] += a0 * b2; acc[0][3] += a0 * b3;
      acc[1][0] += a1 * b0; acc[1][1] += a1 * b1; acc[1][2] += a1 * b2; acc[1][3] += a1 * b3;
      acc[2][0] += a2 * b0; acc[2][1] += a2 * b1; acc[2][2] += a2 * b2; acc[2][3] += a2 * b3;
      acc[3][0] += a3 * b0; acc[3][1] += a3 * b1; acc[3][2] += a3 * b2; acc[3][3] += a3 * b3;
    }
    __syncthreads();
  }
#pragma unroll
  for (int i = 0; i < 4; ++i) {
    int r = mt * 64 + ty * 4 + i;
    int c = nt * 64 + tx * 4;
    float4 v = make_float4(acc[i][0] + bc[c + 0], acc[i][1] + bc[c + 1],
                           acc[i][2] + bc[c + 2], acc[i][3] + bc[c + 3]);
    *(float4*)(fq + (size_t)r * EE + c) = v;
  }
}

// ---------------- K_cvt: f32 rows -> 3-plane bf16 MFMA-fragment layout ----------------
// grid (64 tiles, 8 b), block 256 (4 waves; wave = one K=32 slice k0).
// dst chunk layout: [b][tile][k0][plane][lane][8bf16]; chunk = 1024B, lane-linear.
// Split x = h + m + l by repeated bf16 bit-truncation (each chunk ~8 mantissa bits).
__global__ __launch_bounds__(256) void k_cvt(const float* __restrict__ src,
                                             short* __restrict__ dst) {
  int t = blockIdx.x, b = blockIdx.y;
  int w = threadIdx.x >> 6, l = threadIdx.x & 63;
  int r = min(t * 16 + (l & 15), NN - 1);
  int k = w * 32 + (l >> 4) * 8;
  const float* sp = src + ((size_t)b * NN + r) * EE + k;
  float4 v0 = *(const float4*)sp;
  float4 v1 = *(const float4*)(sp + 4);
  float x[8] = {v0.x, v0.y, v0.z, v0.w, v1.x, v1.y, v1.z, v1.w};
  short8 hv, mv, lv;
#pragma unroll
  for (int j = 0; j < 8; ++j) {
    float xv = x[j];
    unsigned uh = __float_as_uint(xv) & 0xFFFF0000u;
    hv[j] = (short)(uh >> 16);
    float r1 = xv - __uint_as_float(uh);
    unsigned um = __float_as_uint(r1) & 0xFFFF0000u;
    mv[j] = (short)(um >> 16);
    float r2 = r1 - __uint_as_float(um);
    lv[j] = (short)(__float_as_uint(r2) >> 16);
  }
  short* dbase = dst + ((size_t)b * 393216 + (size_t)((t * 4 + w) * 3) * 512 + l * 8);
  *(short8*)(dbase)        = hv;
  *(short8*)(dbase + 512)  = mv;
  *(short8*)(dbase + 1024) = lv;
}

// ---------------- K5: score GEMM via split-bf16 MFMA + tanh clip + exp + partials -------
// grid (8 nt, 16 gt, 8 b), block 256 = 4 waves; wave w owns g-rows [gt*64+w*16, +16) x 128 n.
// 6 MFMA products (h·h, h·m, m·h, m·m, h·l, l·h) reconstruct fp32 to ~2^-22 relative.
// C/D layout: col = lane&15, row = (lane>>4)*4 + reg  [m89-verified].
__global__ __launch_bounds__(256) void k_score(const short* __restrict__ fq3,
                                               const short* __restrict__ emb3,
                                               const float* __restrict__ mask,
                                               float* __restrict__ out,
                                               float* __restrict__ part) {
  int nt = blockIdx.x, gt = blockIdx.y, b = blockIdx.z;
  int w = threadIdx.x >> 6, l = threadIdx.x & 63;
  int gtile = gt * 4 + w;
  const short* ab = fq3 + ((size_t)b * 393216 + (size_t)gtile * 4 * 3 * 512 + l * 8);
  const short* bb = emb3 + ((size_t)b * 393216 + (size_t)nt * 8 * 4 * 3 * 512 + l * 8);
  f32x4 acc[8] = {};
#pragma unroll
  for (int k0 = 0; k0 < 4; ++k0) {
    short8 ah = *(const short8*)(ab + (k0 * 3 + 0) * 512);
    short8 am = *(const short8*)(ab + (k0 * 3 + 1) * 512);
    short8 al = *(const short8*)(ab + (k0 * 3 + 2) * 512);
#pragma unroll
    for (int c = 0; c < 8; ++c) {
      const short* bp = bb + (size_t)((c * 4 + k0) * 3) * 512;
      short8 bh = *(const short8*)(bp);
      short8 bm = *(const short8*)(bp + 512);
      short8 bl = *(const short8*)(bp + 1024);
      acc[c] = __builtin_amdgcn_mfma_f32_16x16x32_bf16(ah, bh, acc[c], 0, 0, 0);
      acc[c] = __builtin_amdgcn_mfma_f32_16x16x32_bf16(am, bh, acc[c], 0, 0, 0);
      acc[c] = __builtin_amdgcn_mfma_f32_16x16x32_bf16(ah, bm, acc[c], 0, 0, 0);
      acc[c] = __builtin_amdgcn_mfma_f32_16x16x32_bf16(am, bm, acc[c], 0, 0, 0);
      acc[c] = __builtin_amdgcn_mfma_f32_16x16x32_bf16(al, bh, acc[c], 0, 0, 0);
      acc[c] = __builtin_amdgcn_mfma_f32_16x16x32_bf16(ah, bl, acc[c], 0, 0, 0);
    }
  }
  const float rs = 0.08838834764831845f;  // 1/sqrt(128)
  const float NEGINF = -__builtin_inff();
  int q = l >> 4, cl = l & 15;
  int gb = gt * 64 + w * 16 + q * 4;
  size_t brow = (size_t)b * GG;
#pragma unroll
  for (int r = 0; r < 4; ++r) {
    int g = gb + r;
    bool gv = (g < GG);
    size_t row = (brow + (gv ? g : GG - 1)) * (size_t)NN;
    float rsum = 0.f;
    float ev[8];
#pragma unroll
    for (int c = 0; c < 8; ++c) {
      int n = nt * 128 + c * 16 + cl;
      float mvv = (gv && n < NN) ? mask[row + n] : NEGINF;
      float sc = acc[c][r] * rs;
      float u = __expf(2.f * sc);
      float th = 1.f - 2.f * __builtin_amdgcn_rcpf(u + 1.f);
      float e = __expf(10.f * th + mvv);   // invalid -> exp(-inf) = 0
      ev[c] = e;
      rsum += e;
    }
    if (gv) {
#pragma unroll
      for (int c = 0; c < 8; ++c) {
        int n = nt * 128 + c * 16 + cl;
        if (n < NN) out[row + n] = ev[c];
      }
    }
#pragma unroll
    for (int off = 1; off < 16; off <<= 1) rsum += __shfl_xor(rsum, off);
    if (cl == 0 && gv) part[(brow + g) * 8 + nt] = rsum;
  }
}

// ---------------- K6: normalize: probs = exp / rowsum ----------------
// grid 8000 (one block per (b,g) row), block 256
__global__ __launch_bounds__(256) void k_norm(const float* __restrict__ part,
                                              float* __restrict__ out) {
  int row = blockIdx.x;
  __shared__ float ssum;
  int t = threadIdx.x;
  float v = (t < 8) ? part[(size_t)row * 8 + t] : 0.f;
#pragma unroll
  for (int off = 1; off < 8; off <<= 1) v += __shfl_xor(v, off);
  if (t == 0) ssum = v;
  __syncthreads();
  float inv = 1.f / ssum;
  if (t < 250) {
    float4* o = (float4*)(out + (size_t)row * NN);
    float4 x = o[t];
    x.x *= inv; x.y *= inv; x.z *= inv; x.w *= inv;
    o[t] = x;
  }
}

extern "C" void kernel_launch(void* const* d_in, const int* in_sizes, int n_in,
                              void* d_out, int out_size, void* d_ws, size_t ws_size,
                              hipStream_t stream) {
  const int*   last_node = (const int*)d_in[0];
  const float* coords    = (const float*)d_in[1];
  const float* emb       = (const float*)d_in[2];
  const float* mask      = (const float*)d_in[3];
  const float* Wqg       = (const float*)d_in[4];
  const float* Wqf       = (const float*)d_in[5];
  const float* Wql       = (const float*)d_in[6];
  const float* Wk        = (const float*)d_in[7];
  const float* Wv        = (const float*)d_in[8];
  const float* Wc        = (const float*)d_in[9];
  const float* bc        = (const float*)d_in[10];
  float* out = (float*)d_out;
  float* ws  = (float*)d_ws;

  float* qg    = ws + OFF_QG;
  float* Karr  = ws + OFF_K;
  float* Varr  = ws + OFF_V;
  float* QFL   = ws + OFF_QFL;
  float* outg  = ws + OFF_OUTG;
  float* fq    = ws + OFF_FQ;
  float* part  = ws + OFF_PART;
  float* gpart = ws + OFF_GPART;
  short* emb3  = (short*)(ws + OFF_K);    // aliases Karr/Varr (dead after k_glimpse)
  short* fq3   = (short*)(ws + OFF_QFL);  // aliases QFL/outg (dead after k_comb)

  k_gq1<<<dim3(BD, 25), dim3(256), 0, stream>>>(emb, gpart);
  k_gq2<<<dim3(BD), dim3(128), 0, stream>>>(gpart, Wqg, qg);
  k_proj<<<dim3(125, 6), dim3(256), 0, stream>>>(emb, Wk, Wv, Wqf, Wql, Karr, Varr, QFL);
  k_glimpse<<<dim3(2000), dim3(256), 0, stream>>>(last_node, coords, mask, qg, QFL, Karr, Varr, outg);
  k_comb<<<dim3(125, 2), dim3(256), 0, stream>>>(outg, Wc, bc, fq);
  k_cvt<<<dim3(64, BD), dim3(256), 0, stream>>>(emb, emb3);
  k_cvt<<<dim3(64, BD), dim3(256), 0, stream>>>(fq, fq3);
  k_score<<<dim3(8, 16, 8), dim3(256), 0, stream>>>(fq3, emb3, mask, out, part);
  k_norm<<<dim3(8000), dim3(256), 0, stream>>>(part, out);
}

// Round 9
// 207.349 us; speedup vs baseline: 1.0142x; 1.0142x over previous
//
#include <hip/hip_runtime.h>
#include <math.h>

#define BD 8
#define NN 1000
#define GG 1000
#define EE 128

typedef unsigned long long u64;
typedef __attribute__((ext_vector_type(8))) short short8;   // 8 bf16 (4 VGPRs)
typedef __attribute__((ext_vector_type(4))) float f32x4;

// ws layout (floats)
#define OFF_QG    0                       // B*128
#define OFF_K     1024                    // 8000*128
#define OFF_V     (OFF_K + 1024000)
#define OFF_QFL   (OFF_V + 1024000)
#define OFF_OUTG  (OFF_QFL + 1024000)
#define OFF_FQ    (OFF_OUTG + 1024000)
#define OFF_PART  (OFF_FQ + 1024000)      // 8000*8
#define OFF_GPART (OFF_PART + 64000)      // 8*25*128
// After k_glimpse, Karr/Varr are dead -> emb3 frag buffer aliases OFF_K.
// fq3 (written by k_comb) lives at OFF_FQ (3 MB shorts < 4 MB float slot).

// ---------------- K1a: partial row sums of embeddings (B x 25 x 128) ----------------
__global__ __launch_bounds__(256) void k_gq1(const float* __restrict__ emb,
                                             float* __restrict__ gpart) {
  __shared__ float ps[2][128];
  int b = blockIdx.x, blk = blockIdx.y;
  int t = threadIdx.x;
  int e = t & 127, p = t >> 7;
  const float* eb = emb + ((size_t)b * NN + blk * 40 + p * 20) * EE + e;
  float s = 0.f;
#pragma unroll 4
  for (int n = 0; n < 20; ++n) s += eb[(size_t)n * EE];
  ps[p][e] = s;
  __syncthreads();
  if (t < 128) gpart[(b * 25 + blk) * 128 + t] = ps[0][t] + ps[1][t];
}

// ---------------- K1b: finalize mean + q_graph = mean @ Wqg^T ----------------
__global__ __launch_bounds__(128) void k_gq2(const float* __restrict__ gpart,
                                             const float* __restrict__ Wqg,
                                             float* __restrict__ qg) {
  __shared__ float ge[128];
  int b = blockIdx.x, t = threadIdx.x;
  float s = 0.f;
#pragma unroll 5
  for (int j = 0; j < 25; ++j) s += gpart[(b * 25 + j) * 128 + t];
  ge[t] = s * (1.f / 1000.f);
  __syncthreads();
  const float* wr = Wqg + (size_t)t * EE;
  float acc = 0.f;
#pragma unroll 8
  for (int k = 0; k < 128; ++k) acc += ge[k] * wr[k];
  qg[b * EE + t] = acc;
}

// ---------------- K2: fused projection GEMM  P = emb @ [Wk;Wv;Wqf+Wql]^T ----------------
__global__ __launch_bounds__(256) void k_proj(const float* __restrict__ emb,
                                              const float* __restrict__ Wk,
                                              const float* __restrict__ Wv,
                                              const float* __restrict__ Wqf,
                                              const float* __restrict__ Wql,
                                              float* __restrict__ Karr,
                                              float* __restrict__ Varr,
                                              float* __restrict__ QFL) {
  __shared__ float Als[16][68];
  __shared__ float Bls[16][68];
  int mt = blockIdx.x, nt = blockIdx.y;
  int t = threadIdx.x;
  int ty = t >> 4, tx = t & 15;
  int row4 = t >> 2, kq = t & 3;
  float acc[4][4] = {};
  for (int k0 = 0; k0 < 128; k0 += 16) {
    const float* ap = emb + (size_t)(mt * 64 + row4) * EE + k0 + kq * 4;
    float4 av = *(const float4*)ap;
    int j = nt * 64 + row4;
    float4 bv;
    if (j < 128) {
      bv = *(const float4*)(Wk + (size_t)j * EE + k0 + kq * 4);
    } else if (j < 256) {
      bv = *(const float4*)(Wv + (size_t)(j - 128) * EE + k0 + kq * 4);
    } else {
      float4 f = *(const float4*)(Wqf + (size_t)(j - 256) * EE + k0 + kq * 4);
      float4 l = *(const float4*)(Wql + (size_t)(j - 256) * EE + k0 + kq * 4);
      bv = make_float4(f.x + l.x, f.y + l.y, f.z + l.z, f.w + l.w);
    }
    Als[kq * 4 + 0][row4] = av.x; Als[kq * 4 + 1][row4] = av.y;
    Als[kq * 4 + 2][row4] = av.z; Als[kq * 4 + 3][row4] = av.w;
    Bls[kq * 4 + 0][row4] = bv.x; Bls[kq * 4 + 1][row4] = bv.y;
    Bls[kq * 4 + 2][row4] = bv.z; Bls[kq * 4 + 3][row4] = bv.w;
    __syncthreads();
#pragma unroll
    for (int k = 0; k < 16; ++k) {
      float a0 = Als[k][ty * 4 + 0], a1 = Als[k][ty * 4 + 1];
      float a2 = Als[k][ty * 4 + 2], a3 = Als[k][ty * 4 + 3];
      float b0 = Bls[k][tx * 4 + 0], b1 = Bls[k][tx * 4 + 1];
      float b2 = Bls[k][tx * 4 + 2], b3 = Bls[k][tx * 4 + 3];
      acc[0][0] += a0 * b0; acc[0][1] += a0 * b1; acc[0][2] += a0 * b2; acc[0][3] += a0 * b3;
      acc[1][0] += a1 * b0; acc[1][1] += a1 * b1; acc[1][2] += a1 * b2; acc[1][3] += a1 * b3;
      acc[2][0] += a2 * b0; acc[2][1] += a2 * b1; acc[2][2] += a2 * b2; acc[2][3] += a2 * b3;
      acc[3][0] += a3 * b0; acc[3][1] += a3 * b1; acc[3][2] += a3 * b2; acc[3][3] += a3 * b3;
    }
    __syncthreads();
  }
  float* outp; int cb;
  if (nt < 2)      { outp = Karr; cb = nt * 64; }
  else if (nt < 4) { outp = Varr; cb = (nt - 2) * 64; }
  else             { outp = QFL;  cb = (nt - 4) * 64; }
#pragma unroll
  for (int i = 0; i < 4; ++i) {
    int r = mt * 64 + ty * 4 + i;
    float4 v = make_float4(acc[i][0], acc[i][1], acc[i][2], acc[i][3]);
    *(float4*)(outp + (size_t)r * EE + cb + tx * 4) = v;
  }
}

// ----- u32 wave-min helpers (DPP row rotations + shfl for 16/32) -----
template <int CTRL>
__device__ __forceinline__ unsigned dpp_minu(unsigned x) {
  unsigned o = (unsigned)__builtin_amdgcn_update_dpp(0, (int)x, CTRL, 0xf, 0xf, false);
  return o < x ? o : x;
}
__device__ __forceinline__ unsigned wave_min_u32(unsigned x) {
  x = dpp_minu<0x121>(x);
  x = dpp_minu<0x122>(x);
  x = dpp_minu<0x124>(x);
  x = dpp_minu<0x128>(x);
  unsigned o = (unsigned)__shfl_xor((int)x, 16); x = o < x ? o : x;
  o = (unsigned)__shfl_xor((int)x, 32); x = o < x ? o : x;
  return x;
}

// ---------------- K3: per-(b,g) KNN + glimpse attention -> outg (B,G,128) ----------------
__global__ __launch_bounds__(256) void k_glimpse(const int* __restrict__ last_node,
                                                 const float* __restrict__ coords,
                                                 const float* __restrict__ mask,
                                                 const float* __restrict__ qg,
                                                 const float* __restrict__ QFL,
                                                 const float* __restrict__ Karr,
                                                 const float* __restrict__ Varr,
                                                 float* __restrict__ outg) {
  __shared__ float pbuf[4][128];
  __shared__ int   nbuf[4][16];
  const float INF = __builtin_inff();
  int wv = threadIdx.x >> 6;
  int lane = threadIdx.x & 63;
  int wid = (blockIdx.x * blockDim.x + threadIdx.x) >> 6;
  int b = wid / GG, g = wid % GG;
  int last = last_node[b * GG + g];
  const float2* cb2 = (const float2*)(coords + (size_t)b * NN * 2);
  float2 lc = cb2[last];
  float lc2 = lc.x * lc.x + lc.y * lc.y;
  const float* mrow = mask + ((size_t)b * GG + g) * NN;
  unsigned d2u[16];
#pragma unroll
  for (int i = 0; i < 16; ++i) {
    int n = lane + (i << 6);
    unsigned k = 0xFFFFFFFFu;
    if (n < NN) {
      float2 c = cb2[n];
      float d2 = lc2 + (c.x * c.x + c.y * c.y) - 2.f * (lc.x * c.x + lc.y * c.y);
      d2 = fmaxf(d2, 0.f);
      k = __float_as_uint(d2);
      if (mrow[n] == -INF) k = 0x7F800000u;
    }
    d2u[i] = k;
  }
  int h = lane >> 3;
  int kk = lane & 7;
  int n0sel = 0, n1sel = 0;
  for (int s = 0; s < 16; ++s) {
    unsigned bv = d2u[0]; int bs = 0;
#pragma unroll
    for (int i = 1; i < 16; ++i) {
      bool better = d2u[i] < bv;
      bv = better ? d2u[i] : bv;
      bs = better ? i : bs;
    }
    unsigned wm = wave_min_u32(bv);
    u64 tied = __ballot(bv == wm);
    int wn;
    if (__popcll(tied) == 1) {
      int wl = (int)__builtin_ctzll(tied);
      int ws = __builtin_amdgcn_readlane(bs, wl);
      wn = wl + (ws << 6);
    } else {
      unsigned cn = (bv == wm) ? (unsigned)(lane + (bs << 6)) : 0x7FFFFFFFu;
      cn = wave_min_u32(cn);
      wn = (int)__builtin_amdgcn_readfirstlane((int)cn);
    }
    n0sel = (s == kk) ? wn : n0sel;
    n1sel = (s == kk + 8) ? wn : n1sel;
    int iw = wn >> 6;
    bool me = (lane == (wn & 63));
#pragma unroll
    for (int i = 0; i < 16; ++i)
      if (i == iw && me) d2u[i] = 0xFFFFFFFFu;
  }
  float qh[16];
  {
    const float4* qg4 = (const float4*)(qg + b * EE + h * 16);
    const float4* qf4 = (const float4*)(QFL + ((size_t)b * NN + last) * EE + h * 16);
#pragma unroll
    for (int u = 0; u < 4; ++u) {
      float4 a = qg4[u], c = qf4[u];
      qh[u * 4 + 0] = a.x + c.x; qh[u * 4 + 1] = a.y + c.y;
      qh[u * 4 + 2] = a.z + c.z; qh[u * 4 + 3] = a.w + c.w;
    }
  }
  const float* Kb = Karr + (size_t)b * NN * EE;
  float s0 = 0.f, s1 = 0.f;
  {
    const float4* k04 = (const float4*)(Kb + (size_t)n0sel * EE + h * 16);
    const float4* k14 = (const float4*)(Kb + (size_t)n1sel * EE + h * 16);
    float4 ka[4], kb[4];
#pragma unroll
    for (int u = 0; u < 4; ++u) { ka[u] = k04[u]; kb[u] = k14[u]; }
#pragma unroll
    for (int u = 0; u < 4; ++u) {
      s0 += qh[u * 4 + 0] * ka[u].x; s0 += qh[u * 4 + 1] * ka[u].y;
      s0 += qh[u * 4 + 2] * ka[u].z; s0 += qh[u * 4 + 3] * ka[u].w;
      s1 += qh[u * 4 + 0] * kb[u].x; s1 += qh[u * 4 + 1] * kb[u].y;
      s1 += qh[u * 4 + 2] * kb[u].z; s1 += qh[u * 4 + 3] * kb[u].w;
    }
  }
  s0 *= 0.25f; s1 *= 0.25f;
  float m = fmaxf(s0, s1);
#pragma unroll
  for (int off = 1; off < 8; off <<= 1) m = fmaxf(m, __shfl_xor(m, off));
  float e0 = __expf(s0 - m), e1 = __expf(s1 - m);
  float se = e0 + e1;
#pragma unroll
  for (int off = 1; off < 8; off <<= 1) se += __shfl_xor(se, off);
  float p0 = e0 / se, p1 = e1 / se;
  pbuf[wv][h * 16 + kk] = p0;
  pbuf[wv][h * 16 + kk + 8] = p1;
  if (h == 0) { nbuf[wv][kk] = n0sel; nbuf[wv][kk + 8] = n1sel; }
  const float* Vb = Varr + (size_t)b * NN * EE;
  float o0 = 0.f, o1 = 0.f;
#pragma unroll
  for (int c = 0; c < 2; ++c) {
    int nk[8]; float pk[8]; float2 vv[8];
#pragma unroll
    for (int j = 0; j < 8; ++j) { nk[j] = nbuf[wv][c * 8 + j]; pk[j] = pbuf[wv][h * 16 + c * 8 + j]; }
#pragma unroll
    for (int j = 0; j < 8; ++j)
      vv[j] = *(const float2*)(Vb + (size_t)nk[j] * EE + h * 16 + kk * 2);
#pragma unroll
    for (int j = 0; j < 8; ++j) { o0 += pk[j] * vv[j].x; o1 += pk[j] * vv[j].y; }
  }
  *(float2*)(outg + ((size_t)b * GG + g) * EE + h * 16 + kk * 2) = make_float2(o0, o1);
}

// ---------------- K4: final_q = outg @ W_comb^T + b_comb -> fq3 fragments directly ------
// grid 125, block 256, tile 64 rows x 128 cols, thread 4x8 (8 consecutive cols).
// Emits 3-plane bf16 split (identical arithmetic to old k_cvt) - no f32 fq roundtrip.
__global__ __launch_bounds__(256) void k_comb(const float* __restrict__ outg,
                                              const float* __restrict__ Wc,
                                              const float* __restrict__ bc,
                                              short* __restrict__ fq3) {
  __shared__ float Als[16][68];
  __shared__ float Bls[16][132];
  int mt = blockIdx.x;
  int t = threadIdx.x;
  int ty = t >> 4, tx = t & 15;
  int la = t >> 2, akq = t & 3;          // A stage: row 0..63, k-quarter
  int lb = t >> 1, bkq = t & 1;          // B stage: row 0..127, k-half
  const float* apos = outg + (size_t)(mt * 64 + la) * EE + akq * 4;
  const float* bpos = Wc + (size_t)lb * EE + bkq * 8;
  float acc[4][8] = {};
  float4 pa  = *(const float4*)apos;
  float4 pb0 = *(const float4*)bpos;
  float4 pb1 = *(const float4*)(bpos + 4);
  for (int k0 = 0; k0 < 128; k0 += 16) {
    __syncthreads();
    Als[akq * 4 + 0][la] = pa.x;  Als[akq * 4 + 1][la] = pa.y;
    Als[akq * 4 + 2][la] = pa.z;  Als[akq * 4 + 3][la] = pa.w;
    Bls[bkq * 8 + 0][lb] = pb0.x; Bls[bkq * 8 + 1][lb] = pb0.y;
    Bls[bkq * 8 + 2][lb] = pb0.z; Bls[bkq * 8 + 3][lb] = pb0.w;
    Bls[bkq * 8 + 4][lb] = pb1.x; Bls[bkq * 8 + 5][lb] = pb1.y;
    Bls[bkq * 8 + 6][lb] = pb1.z; Bls[bkq * 8 + 7][lb] = pb1.w;
    __syncthreads();
    if (k0 < 112) {
      pa  = *(const float4*)(apos + k0 + 16);
      pb0 = *(const float4*)(bpos + k0 + 16);
      pb1 = *(const float4*)(bpos + k0 + 20);
    }
#pragma unroll
    for (int k = 0; k < 16; ++k) {
      float4 av  = *(const float4*)&Als[k][ty * 4];
      float4 bv0 = *(const float4*)&Bls[k][tx * 8];
      float4 bv1 = *(const float4*)&Bls[k][tx * 8 + 4];
      float af[4] = {av.x, av.y, av.z, av.w};
      float bf[8] = {bv0.x, bv0.y, bv0.z, bv0.w, bv1.x, bv1.y, bv1.z, bv1.w};
#pragma unroll
      for (int i = 0; i < 4; ++i)
#pragma unroll
        for (int j = 0; j < 8; ++j) acc[i][j] += af[i] * bf[j];
    }
  }
  // epilogue: + bias, 3-way bf16 split, store fragment layout
  int c0 = tx * 8;
  float4 b0 = *(const float4*)(bc + c0);
  float4 b1 = *(const float4*)(bc + c0 + 4);
  float bias[8] = {b0.x, b0.y, b0.z, b0.w, b1.x, b1.y, b1.z, b1.w};
  int k0f = tx >> 2;            // c0/32
  int lsub = tx & 3;            // (c0&31)/8
#pragma unroll
  for (int i = 0; i < 4; ++i) {
    int r = mt * 64 + ty * 4 + i;      // global row 0..7999
    int b = r / GG;
    int g = r - b * GG;
    short8 hv, mv, lv;
#pragma unroll
    for (int j = 0; j < 8; ++j) {
      float xv = acc[i][j] + bias[j];
      unsigned uh = __float_as_uint(xv) & 0xFFFF0000u;
      hv[j] = (short)(uh >> 16);
      float r1 = xv - __uint_as_float(uh);
      unsigned um = __float_as_uint(r1) & 0xFFFF0000u;
      mv[j] = (short)(um >> 16);
      float r2 = r1 - __uint_as_float(um);
      lv[j] = (short)(__float_as_uint(r2) >> 16);
    }
    int tile = g >> 4;
    int lanefrag = (g & 15) + lsub * 16;
    short* dbase = fq3 + ((size_t)b * 393216 + (size_t)((tile * 4 + k0f) * 3) * 512 + lanefrag * 8);
    *(short8*)(dbase)        = hv;
    *(short8*)(dbase + 512)  = mv;
    *(short8*)(dbase + 1024) = lv;
  }
}

// ---------------- K_cvt: f32 rows -> 3-plane bf16 MFMA-fragment layout (emb only) -------
__global__ __launch_bounds__(256) void k_cvt(const float* __restrict__ src,
                                             short* __restrict__ dst) {
  int t = blockIdx.x, b = blockIdx.y;
  int w = threadIdx.x >> 6, l = threadIdx.x & 63;
  int r = min(t * 16 + (l & 15), NN - 1);
  int k = w * 32 + (l >> 4) * 8;
  const float* sp = src + ((size_t)b * NN + r) * EE + k;
  float4 v0 = *(const float4*)sp;
  float4 v1 = *(const float4*)(sp + 4);
  float x[8] = {v0.x, v0.y, v0.z, v0.w, v1.x, v1.y, v1.z, v1.w};
  short8 hv, mv, lv;
#pragma unroll
  for (int j = 0; j < 8; ++j) {
    float xv = x[j];
    unsigned uh = __float_as_uint(xv) & 0xFFFF0000u;
    hv[j] = (short)(uh >> 16);
    float r1 = xv - __uint_as_float(uh);
    unsigned um = __float_as_uint(r1) & 0xFFFF0000u;
    mv[j] = (short)(um >> 16);
    float r2 = r1 - __uint_as_float(um);
    lv[j] = (short)(__float_as_uint(r2) >> 16);
  }
  short* dbase = dst + ((size_t)b * 393216 + (size_t)((t * 4 + w) * 3) * 512 + l * 8);
  *(short8*)(dbase)        = hv;
  *(short8*)(dbase + 512)  = mv;
  *(short8*)(dbase + 1024) = lv;
}

// ---------------- K5: score GEMM via split-bf16 MFMA; LDS-transposed coalesced epilogue --
// grid (8 nt, 16 gt, 8 b), block 256 = 4 waves; wave w: g-rows [gt*64+w*16,+16) x 128 n.
// epilogue: acc -> wave-private LDS [16][132] -> row-contiguous read (1KB/instr) ->
//           float4 mask load + exp + float4 out store; rowsum via 5 half-wave shuffles.
__global__ __launch_bounds__(256, 2) void k_score(const short* __restrict__ fq3,
                                                  const short* __restrict__ emb3,
                                                  const float* __restrict__ mask,
                                                  float* __restrict__ out,
                                                  float* __restrict__ part) {
  __shared__ float xs[4][16][132];
  int nt = blockIdx.x, gt = blockIdx.y, b = blockIdx.z;
  int w = threadIdx.x >> 6, l = threadIdx.x & 63;
  int gtile = gt * 4 + w;
  const short* ab = fq3 + ((size_t)b * 393216 + (size_t)gtile * 6144 + l * 8);
  const short* bb = emb3 + ((size_t)b * 393216 + (size_t)nt * 8 * 6144 + l * 8);
  f32x4 acc[8] = {};
#pragma unroll
  for (int k0 = 0; k0 < 4; ++k0) {
    short8 ah = *(const short8*)(ab + (k0 * 3 + 0) * 512);
    short8 am = *(const short8*)(ab + (k0 * 3 + 1) * 512);
    short8 al = *(const short8*)(ab + (k0 * 3 + 2) * 512);
#pragma unroll
    for (int c = 0; c < 8; ++c) {
      const short* bp = bb + (size_t)(c * 6144 + k0 * 1536);
      short8 bh = *(const short8*)(bp);
      short8 bm = *(const short8*)(bp + 512);
      short8 bl = *(const short8*)(bp + 1024);
      acc[c] = __builtin_amdgcn_mfma_f32_16x16x32_bf16(ah, bh, acc[c], 0, 0, 0);
      acc[c] = __builtin_amdgcn_mfma_f32_16x16x32_bf16(am, bh, acc[c], 0, 0, 0);
      acc[c] = __builtin_amdgcn_mfma_f32_16x16x32_bf16(ah, bm, acc[c], 0, 0, 0);
      acc[c] = __builtin_amdgcn_mfma_f32_16x16x32_bf16(am, bm, acc[c], 0, 0, 0);
      acc[c] = __builtin_amdgcn_mfma_f32_16x16x32_bf16(al, bh, acc[c], 0, 0, 0);
      acc[c] = __builtin_amdgcn_mfma_f32_16x16x32_bf16(ah, bl, acc[c], 0, 0, 0);
    }
  }
  // stage to wave-private LDS (C/D layout: col = lane&15, row = (lane>>4)*4 + reg)
  int q = l >> 4, cl = l & 15;
#pragma unroll
  for (int c = 0; c < 8; ++c)
#pragma unroll
    for (int r = 0; r < 4; ++r)
      xs[w][q * 4 + r][c * 16 + cl] = acc[c][r];
  // transposed, coalesced epilogue (no barrier: wave-private region)
  const float rs = 0.08838834764831845f;  // 1/sqrt(128)
  const float NEGINF = -__builtin_inff();
  int half = l >> 5, ln = l & 31;
  int n0 = nt * 128 + ln * 4;
  bool nv = (n0 < NN);                    // 1000 % 4 == 0: chunk-aligned guard
  size_t brow = (size_t)b * GG;
#pragma unroll
  for (int it = 0; it < 8; ++it) {
    int row = it * 2 + half;              // 0..15 within tile
    int g = gt * 64 + w * 16 + row;
    bool gv = (g < GG);
    size_t roff = (brow + (gv ? g : GG - 1)) * (size_t)NN;
    f32x4 v = *(const f32x4*)&xs[w][row][ln * 4];
    float4 mvv;
    if (gv && nv) mvv = *(const float4*)(mask + roff + n0);
    else mvv = make_float4(NEGINF, NEGINF, NEGINF, NEGINF);
    float mva[4] = {mvv.x, mvv.y, mvv.z, mvv.w};
    float e[4];
    float rsum = 0.f;
#pragma unroll
    for (int j = 0; j < 4; ++j) {
      float sc = v[j] * rs;
      float u = __expf(2.f * sc);
      float th = 1.f - 2.f * __builtin_amdgcn_rcpf(u + 1.f);
      e[j] = __expf(10.f * th + mva[j]);  // invalid -> exp(-inf) = 0
      rsum += e[j];
    }
    if (gv && nv) *(float4*)(out + roff + n0) = make_float4(e[0], e[1], e[2], e[3]);
#pragma unroll
    for (int off = 1; off < 32; off <<= 1) rsum += __shfl_xor(rsum, off);
    if (ln == 0 && gv) part[(brow + g) * 8 + nt] = rsum;
  }
}

// ---------------- K6: normalize: probs = exp / rowsum ----------------
__global__ __launch_bounds__(256) void k_norm(const float* __restrict__ part,
                                              float* __restrict__ out) {
  int row = blockIdx.x;
  __shared__ float ssum;
  int t = threadIdx.x;
  float v = (t < 8) ? part[(size_t)row * 8 + t] : 0.f;
#pragma unroll
  for (int off = 1; off < 8; off <<= 1) v += __shfl_xor(v, off);
  if (t == 0) ssum = v;
  __syncthreads();
  float inv = 1.f / ssum;
  if (t < 250) {
    float4* o = (float4*)(out + (size_t)row * NN);
    float4 x = o[t];
    x.x *= inv; x.y *= inv; x.z *= inv; x.w *= inv;
    o[t] = x;
  }
}

extern "C" void kernel_launch(void* const* d_in, const int* in_sizes, int n_in,
                              void* d_out, int out_size, void* d_ws, size_t ws_size,
                              hipStream_t stream) {
  const int*   last_node = (const int*)d_in[0];
  const float* coords    = (const float*)d_in[1];
  const float* emb       = (const float*)d_in[2];
  const float* mask      = (const float*)d_in[3];
  const float* Wqg       = (const float*)d_in[4];
  const float* Wqf       = (const float*)d_in[5];
  const float* Wql       = (const float*)d_in[6];
  const float* Wk        = (const float*)d_in[7];
  const float* Wv        = (const float*)d_in[8];
  const float* Wc        = (const float*)d_in[9];
  const float* bc        = (const float*)d_in[10];
  float* out = (float*)d_out;
  float* ws  = (float*)d_ws;

  float* qg    = ws + OFF_QG;
  float* Karr  = ws + OFF_K;
  float* Varr  = ws + OFF_V;
  float* QFL   = ws + OFF_QFL;
  float* outg  = ws + OFF_OUTG;
  float* part  = ws + OFF_PART;
  float* gpart = ws + OFF_GPART;
  short* emb3  = (short*)(ws + OFF_K);    // aliases Karr/Varr (dead after k_glimpse)
  short* fq3   = (short*)(ws + OFF_FQ);   // written by k_comb

  k_gq1<<<dim3(BD, 25), dim3(256), 0, stream>>>(emb, gpart);
  k_gq2<<<dim3(BD), dim3(128), 0, stream>>>(gpart, Wqg, qg);
  k_proj<<<dim3(125, 6), dim3(256), 0, stream>>>(emb, Wk, Wv, Wqf, Wql, Karr, Varr, QFL);
  k_glimpse<<<dim3(2000), dim3(256), 0, stream>>>(last_node, coords, mask, qg, QFL, Karr, Varr, outg);
  k_comb<<<dim3(125), dim3(256), 0, stream>>>(outg, Wc, bc, fq3);
  k_cvt<<<dim3(64, BD), dim3(256), 0, stream>>>(emb, emb3);
  k_score<<<dim3(8, 16, 8), dim3(256), 0, stream>>>(fq3, emb3, mask, out, part);
  k_norm<<<dim3(8000), dim3(256), 0, stream>>>(part, out);
}

// Round 10
// 195.602 us; speedup vs baseline: 1.0751x; 1.0601x over previous
//
#include <hip/hip_runtime.h>
#include <math.h>

#define BD 8
#define NN 1000
#define GG 1000
#define EE 128

typedef unsigned long long u64;
typedef __attribute__((ext_vector_type(8))) short short8;   // 8 bf16 (4 VGPRs)
typedef __attribute__((ext_vector_type(4))) float f32x4;

// ws layout (floats)
#define OFF_QG    0                       // B*128
#define OFF_K     1024                    // 8000*128
#define OFF_V     (OFF_K + 1024000)
#define OFF_QFL   (OFF_V + 1024000)
#define OFF_OUTG  (OFF_QFL + 1024000)
#define OFF_FQ    (OFF_OUTG + 1024000)
#define OFF_PART  (OFF_FQ + 1024000)      // (unused now)
#define OFF_GPART (OFF_PART + 64000)      // 8*25*128
// After k_glimpse, Karr/Varr are dead -> emb3 frag buffer aliases OFF_K.
// fq3 (written by k_comb) lives at OFF_FQ.

// ---------------- K1a: partial row sums of embeddings (B x 25 x 128) ----------------
__global__ __launch_bounds__(256) void k_gq1(const float* __restrict__ emb,
                                             float* __restrict__ gpart) {
  __shared__ float ps[2][128];
  int b = blockIdx.x, blk = blockIdx.y;
  int t = threadIdx.x;
  int e = t & 127, p = t >> 7;
  const float* eb = emb + ((size_t)b * NN + blk * 40 + p * 20) * EE + e;
  float s = 0.f;
#pragma unroll 4
  for (int n = 0; n < 20; ++n) s += eb[(size_t)n * EE];
  ps[p][e] = s;
  __syncthreads();
  if (t < 128) gpart[(b * 25 + blk) * 128 + t] = ps[0][t] + ps[1][t];
}

// ---------------- K1b: finalize mean + q_graph = mean @ Wqg^T ----------------
__global__ __launch_bounds__(128) void k_gq2(const float* __restrict__ gpart,
                                             const float* __restrict__ Wqg,
                                             float* __restrict__ qg) {
  __shared__ float ge[128];
  int b = blockIdx.x, t = threadIdx.x;
  float s = 0.f;
#pragma unroll 5
  for (int j = 0; j < 25; ++j) s += gpart[(b * 25 + j) * 128 + t];
  ge[t] = s * (1.f / 1000.f);
  __syncthreads();
  const float* wr = Wqg + (size_t)t * EE;
  float acc = 0.f;
#pragma unroll 8
  for (int k = 0; k < 128; ++k) acc += ge[k] * wr[k];
  qg[b * EE + t] = acc;
}

// ---------------- K2: fused projection GEMM  P = emb @ [Wk;Wv;Wqf+Wql]^T ----------------
__global__ __launch_bounds__(256) void k_proj(const float* __restrict__ emb,
                                              const float* __restrict__ Wk,
                                              const float* __restrict__ Wv,
                                              const float* __restrict__ Wqf,
                                              const float* __restrict__ Wql,
                                              float* __restrict__ Karr,
                                              float* __restrict__ Varr,
                                              float* __restrict__ QFL) {
  __shared__ float Als[16][68];
  __shared__ float Bls[16][68];
  int mt = blockIdx.x, nt = blockIdx.y;
  int t = threadIdx.x;
  int ty = t >> 4, tx = t & 15;
  int row4 = t >> 2, kq = t & 3;
  float acc[4][4] = {};
  for (int k0 = 0; k0 < 128; k0 += 16) {
    const float* ap = emb + (size_t)(mt * 64 + row4) * EE + k0 + kq * 4;
    float4 av = *(const float4*)ap;
    int j = nt * 64 + row4;
    float4 bv;
    if (j < 128) {
      bv = *(const float4*)(Wk + (size_t)j * EE + k0 + kq * 4);
    } else if (j < 256) {
      bv = *(const float4*)(Wv + (size_t)(j - 128) * EE + k0 + kq * 4);
    } else {
      float4 f = *(const float4*)(Wqf + (size_t)(j - 256) * EE + k0 + kq * 4);
      float4 l = *(const float4*)(Wql + (size_t)(j - 256) * EE + k0 + kq * 4);
      bv = make_float4(f.x + l.x, f.y + l.y, f.z + l.z, f.w + l.w);
    }
    Als[kq * 4 + 0][row4] = av.x; Als[kq * 4 + 1][row4] = av.y;
    Als[kq * 4 + 2][row4] = av.z; Als[kq * 4 + 3][row4] = av.w;
    Bls[kq * 4 + 0][row4] = bv.x; Bls[kq * 4 + 1][row4] = bv.y;
    Bls[kq * 4 + 2][row4] = bv.z; Bls[kq * 4 + 3][row4] = bv.w;
    __syncthreads();
#pragma unroll
    for (int k = 0; k < 16; ++k) {
      float a0 = Als[k][ty * 4 + 0], a1 = Als[k][ty * 4 + 1];
      float a2 = Als[k][ty * 4 + 2], a3 = Als[k][ty * 4 + 3];
      float b0 = Bls[k][tx * 4 + 0], b1 = Bls[k][tx * 4 + 1];
      float b2 = Bls[k][tx * 4 + 2], b3 = Bls[k][tx * 4 + 3];
      acc[0][0] += a0 * b0; acc[0][1] += a0 * b1; acc[0][2] += a0 * b2; acc[0][3] += a0 * b3;
      acc[1][0] += a1 * b0; acc[1][1] += a1 * b1; acc[1][2] += a1 * b2; acc[1][3] += a1 * b3;
      acc[2][0] += a2 * b0; acc[2][1] += a2 * b1; acc[2][2] += a2 * b2; acc[2][3] += a2 * b3;
      acc[3][0] += a3 * b0; acc[3][1] += a3 * b1; acc[3][2] += a3 * b2; acc[3][3] += a3 * b3;
    }
    __syncthreads();
  }
  float* outp; int cb;
  if (nt < 2)      { outp = Karr; cb = nt * 64; }
  else if (nt < 4) { outp = Varr; cb = (nt - 2) * 64; }
  else             { outp = QFL;  cb = (nt - 4) * 64; }
#pragma unroll
  for (int i = 0; i < 4; ++i) {
    int r = mt * 64 + ty * 4 + i;
    float4 v = make_float4(acc[i][0], acc[i][1], acc[i][2], acc[i][3]);
    *(float4*)(outp + (size_t)r * EE + cb + tx * 4) = v;
  }
}

// ----- u32 wave-min helpers (DPP row rotations + shfl for 16/32) -----
template <int CTRL>
__device__ __forceinline__ unsigned dpp_minu(unsigned x) {
  unsigned o = (unsigned)__builtin_amdgcn_update_dpp(0, (int)x, CTRL, 0xf, 0xf, false);
  return o < x ? o : x;
}
__device__ __forceinline__ unsigned wave_min_u32(unsigned x) {
  x = dpp_minu<0x121>(x);
  x = dpp_minu<0x122>(x);
  x = dpp_minu<0x124>(x);
  x = dpp_minu<0x128>(x);
  unsigned o = (unsigned)__shfl_xor((int)x, 16); x = o < x ? o : x;
  o = (unsigned)__shfl_xor((int)x, 32); x = o < x ? o : x;
  return x;
}

// ---------------- K3: per-(b,g) KNN + glimpse attention -> outg (B,G,128) ----------------
__global__ __launch_bounds__(256) void k_glimpse(const int* __restrict__ last_node,
                                                 const float* __restrict__ coords,
                                                 const float* __restrict__ mask,
                                                 const float* __restrict__ qg,
                                                 const float* __restrict__ QFL,
                                                 const float* __restrict__ Karr,
                                                 const float* __restrict__ Varr,
                                                 float* __restrict__ outg) {
  __shared__ float pbuf[4][128];
  __shared__ int   nbuf[4][16];
  const float INF = __builtin_inff();
  int wv = threadIdx.x >> 6;
  int lane = threadIdx.x & 63;
  int wid = (blockIdx.x * blockDim.x + threadIdx.x) >> 6;
  int b = wid / GG, g = wid % GG;
  int last = last_node[b * GG + g];
  const float2* cb2 = (const float2*)(coords + (size_t)b * NN * 2);
  float2 lc = cb2[last];
  float lc2 = lc.x * lc.x + lc.y * lc.y;
  const float* mrow = mask + ((size_t)b * GG + g) * NN;
  unsigned d2u[16];
#pragma unroll
  for (int i = 0; i < 16; ++i) {
    int n = lane + (i << 6);
    unsigned k = 0xFFFFFFFFu;
    if (n < NN) {
      float2 c = cb2[n];
      float d2 = lc2 + (c.x * c.x + c.y * c.y) - 2.f * (lc.x * c.x + lc.y * c.y);
      d2 = fmaxf(d2, 0.f);
      k = __float_as_uint(d2);
      if (mrow[n] == -INF) k = 0x7F800000u;
    }
    d2u[i] = k;
  }
  int h = lane >> 3;
  int kk = lane & 7;
  int n0sel = 0, n1sel = 0;
  for (int s = 0; s < 16; ++s) {
    unsigned bv = d2u[0]; int bs = 0;
#pragma unroll
    for (int i = 1; i < 16; ++i) {
      bool better = d2u[i] < bv;
      bv = better ? d2u[i] : bv;
      bs = better ? i : bs;
    }
    unsigned wm = wave_min_u32(bv);
    u64 tied = __ballot(bv == wm);
    int wn;
    if (__popcll(tied) == 1) {
      int wl = (int)__builtin_ctzll(tied);
      int ws = __builtin_amdgcn_readlane(bs, wl);
      wn = wl + (ws << 6);
    } else {
      unsigned cn = (bv == wm) ? (unsigned)(lane + (bs << 6)) : 0x7FFFFFFFu;
      cn = wave_min_u32(cn);
      wn = (int)__builtin_amdgcn_readfirstlane((int)cn);
    }
    n0sel = (s == kk) ? wn : n0sel;
    n1sel = (s == kk + 8) ? wn : n1sel;
    int iw = wn >> 6;
    bool me = (lane == (wn & 63));
#pragma unroll
    for (int i = 0; i < 16; ++i)
      if (i == iw && me) d2u[i] = 0xFFFFFFFFu;
  }
  float qh[16];
  {
    const float4* qg4 = (const float4*)(qg + b * EE + h * 16);
    const float4* qf4 = (const float4*)(QFL + ((size_t)b * NN + last) * EE + h * 16);
#pragma unroll
    for (int u = 0; u < 4; ++u) {
      float4 a = qg4[u], c = qf4[u];
      qh[u * 4 + 0] = a.x + c.x; qh[u * 4 + 1] = a.y + c.y;
      qh[u * 4 + 2] = a.z + c.z; qh[u * 4 + 3] = a.w + c.w;
    }
  }
  const float* Kb = Karr + (size_t)b * NN * EE;
  float s0 = 0.f, s1 = 0.f;
  {
    const float4* k04 = (const float4*)(Kb + (size_t)n0sel * EE + h * 16);
    const float4* k14 = (const float4*)(Kb + (size_t)n1sel * EE + h * 16);
    float4 ka[4], kb[4];
#pragma unroll
    for (int u = 0; u < 4; ++u) { ka[u] = k04[u]; kb[u] = k14[u]; }
#pragma unroll
    for (int u = 0; u < 4; ++u) {
      s0 += qh[u * 4 + 0] * ka[u].x; s0 += qh[u * 4 + 1] * ka[u].y;
      s0 += qh[u * 4 + 2] * ka[u].z; s0 += qh[u * 4 + 3] * ka[u].w;
      s1 += qh[u * 4 + 0] * kb[u].x; s1 += qh[u * 4 + 1] * kb[u].y;
      s1 += qh[u * 4 + 2] * kb[u].z; s1 += qh[u * 4 + 3] * kb[u].w;
    }
  }
  s0 *= 0.25f; s1 *= 0.25f;
  float m = fmaxf(s0, s1);
#pragma unroll
  for (int off = 1; off < 8; off <<= 1) m = fmaxf(m, __shfl_xor(m, off));
  float e0 = __expf(s0 - m), e1 = __expf(s1 - m);
  float se = e0 + e1;
#pragma unroll
  for (int off = 1; off < 8; off <<= 1) se += __shfl_xor(se, off);
  float p0 = e0 / se, p1 = e1 / se;
  pbuf[wv][h * 16 + kk] = p0;
  pbuf[wv][h * 16 + kk + 8] = p1;
  if (h == 0) { nbuf[wv][kk] = n0sel; nbuf[wv][kk + 8] = n1sel; }
  const float* Vb = Varr + (size_t)b * NN * EE;
  float o0 = 0.f, o1 = 0.f;
#pragma unroll
  for (int c = 0; c < 2; ++c) {
    int nk[8]; float pk[8]; float2 vv[8];
#pragma unroll
    for (int j = 0; j < 8; ++j) { nk[j] = nbuf[wv][c * 8 + j]; pk[j] = pbuf[wv][h * 16 + c * 8 + j]; }
#pragma unroll
    for (int j = 0; j < 8; ++j)
      vv[j] = *(const float2*)(Vb + (size_t)nk[j] * EE + h * 16 + kk * 2);
#pragma unroll
    for (int j = 0; j < 8; ++j) { o0 += pk[j] * vv[j].x; o1 += pk[j] * vv[j].y; }
  }
  *(float2*)(outg + ((size_t)b * GG + g) * EE + h * 16 + kk * 2) = make_float2(o0, o1);
}

// ---------------- K4: final_q = outg @ W_comb^T + b_comb -> fq3 fragments directly ------
__global__ __launch_bounds__(256) void k_comb(const float* __restrict__ outg,
                                              const float* __restrict__ Wc,
                                              const float* __restrict__ bc,
                                              short* __restrict__ fq3) {
  __shared__ float Als[16][68];
  __shared__ float Bls[16][132];
  int mt = blockIdx.x;
  int t = threadIdx.x;
  int ty = t >> 4, tx = t & 15;
  int la = t >> 2, akq = t & 3;
  int lb = t >> 1, bkq = t & 1;
  const float* apos = outg + (size_t)(mt * 64 + la) * EE + akq * 4;
  const float* bpos = Wc + (size_t)lb * EE + bkq * 8;
  float acc[4][8] = {};
  float4 pa  = *(const float4*)apos;
  float4 pb0 = *(const float4*)bpos;
  float4 pb1 = *(const float4*)(bpos + 4);
  for (int k0 = 0; k0 < 128; k0 += 16) {
    __syncthreads();
    Als[akq * 4 + 0][la] = pa.x;  Als[akq * 4 + 1][la] = pa.y;
    Als[akq * 4 + 2][la] = pa.z;  Als[akq * 4 + 3][la] = pa.w;
    Bls[bkq * 8 + 0][lb] = pb0.x; Bls[bkq * 8 + 1][lb] = pb0.y;
    Bls[bkq * 8 + 2][lb] = pb0.z; Bls[bkq * 8 + 3][lb] = pb0.w;
    Bls[bkq * 8 + 4][lb] = pb1.x; Bls[bkq * 8 + 5][lb] = pb1.y;
    Bls[bkq * 8 + 6][lb] = pb1.z; Bls[bkq * 8 + 7][lb] = pb1.w;
    __syncthreads();
    if (k0 < 112) {
      pa  = *(const float4*)(apos + k0 + 16);
      pb0 = *(const float4*)(bpos + k0 + 16);
      pb1 = *(const float4*)(bpos + k0 + 20);
    }
#pragma unroll
    for (int k = 0; k < 16; ++k) {
      float4 av  = *(const float4*)&Als[k][ty * 4];
      float4 bv0 = *(const float4*)&Bls[k][tx * 8];
      float4 bv1 = *(const float4*)&Bls[k][tx * 8 + 4];
      float af[4] = {av.x, av.y, av.z, av.w};
      float bf[8] = {bv0.x, bv0.y, bv0.z, bv0.w, bv1.x, bv1.y, bv1.z, bv1.w};
#pragma unroll
      for (int i = 0; i < 4; ++i)
#pragma unroll
        for (int j = 0; j < 8; ++j) acc[i][j] += af[i] * bf[j];
    }
  }
  int c0 = tx * 8;
  float4 b0 = *(const float4*)(bc + c0);
  float4 b1 = *(const float4*)(bc + c0 + 4);
  float bias[8] = {b0.x, b0.y, b0.z, b0.w, b1.x, b1.y, b1.z, b1.w};
  int k0f = tx >> 2;
  int lsub = tx & 3;
#pragma unroll
  for (int i = 0; i < 4; ++i) {
    int r = mt * 64 + ty * 4 + i;
    int b = r / GG;
    int g = r - b * GG;
    short8 hv, mv, lv;
#pragma unroll
    for (int j = 0; j < 8; ++j) {
      float xv = acc[i][j] + bias[j];
      unsigned uh = __float_as_uint(xv) & 0xFFFF0000u;
      hv[j] = (short)(uh >> 16);
      float r1 = xv - __uint_as_float(uh);
      unsigned um = __float_as_uint(r1) & 0xFFFF0000u;
      mv[j] = (short)(um >> 16);
      float r2 = r1 - __uint_as_float(um);
      lv[j] = (short)(__float_as_uint(r2) >> 16);
    }
    int tile = g >> 4;
    int lanefrag = (g & 15) + lsub * 16;
    short* dbase = fq3 + ((size_t)b * 393216 + (size_t)((tile * 4 + k0f) * 3) * 512 + lanefrag * 8);
    *(short8*)(dbase)        = hv;
    *(short8*)(dbase + 512)  = mv;
    *(short8*)(dbase + 1024) = lv;
  }
}

// ---------------- K_cvt: f32 rows -> 3-plane bf16 MFMA-fragment layout (emb only) -------
__global__ __launch_bounds__(256) void k_cvt(const float* __restrict__ src,
                                             short* __restrict__ dst) {
  int t = blockIdx.x, b = blockIdx.y;
  int w = threadIdx.x >> 6, l = threadIdx.x & 63;
  int r = min(t * 16 + (l & 15), NN - 1);
  int k = w * 32 + (l >> 4) * 8;
  const float* sp = src + ((size_t)b * NN + r) * EE + k;
  float4 v0 = *(const float4*)sp;
  float4 v1 = *(const float4*)(sp + 4);
  float x[8] = {v0.x, v0.y, v0.z, v0.w, v1.x, v1.y, v1.z, v1.w};
  short8 hv, mv, lv;
#pragma unroll
  for (int j = 0; j < 8; ++j) {
    float xv = x[j];
    unsigned uh = __float_as_uint(xv) & 0xFFFF0000u;
    hv[j] = (short)(uh >> 16);
    float r1 = xv - __uint_as_float(uh);
    unsigned um = __float_as_uint(r1) & 0xFFFF0000u;
    mv[j] = (short)(um >> 16);
    float r2 = r1 - __uint_as_float(um);
    lv[j] = (short)(__float_as_uint(r2) >> 16);
  }
  short* dbase = dst + ((size_t)b * 393216 + (size_t)((t * 4 + w) * 3) * 512 + l * 8);
  *(short8*)(dbase)        = hv;
  *(short8*)(dbase + 512)  = mv;
  *(short8*)(dbase + 1024) = lv;
}

// ---------------- K5: score GEMM (split-bf16 MFMA) + tanh/exp + FUSED row-normalize -----
// grid (32 gy, 8 b) = 256 blocks; block 1024 = 16 waves = 2 wg x 8 wn.
// Wave: g-rows [gy*32+wg*16, +16) x n-cols [wn*128, +128). Whole row in one block ->
// softmax denominator via LDS psum + 1 barrier; writes NORMALIZED probs (no k_norm pass).
__global__ __launch_bounds__(1024, 1) void k_score(const short* __restrict__ fq3,
                                                   const short* __restrict__ emb3,
                                                   const float* __restrict__ mask,
                                                   float* __restrict__ out) {
  __shared__ float xs[16][16][36];   // per-wave staging: 16 rows x 32 cols (+4 pad)
  __shared__ float psum[32][8];      // [row-in-block][wn]
  __shared__ float sinv[32];
  int gy = blockIdx.x, b = blockIdx.y;
  int wv = threadIdx.x >> 6, l = threadIdx.x & 63;
  int wg = wv >> 3, wn = wv & 7;
  int gtile = gy * 2 + wg;           // A-tile 0..63 (tile 63 = poison rows >=1000, guarded)
  const short* ab = fq3 + ((size_t)b * 393216 + (size_t)gtile * 6144 + l * 8);
  const short* bb = emb3 + ((size_t)b * 393216 + (size_t)wn * 8 * 6144 + l * 8);
  f32x4 acc[8] = {};
#pragma unroll
  for (int k0 = 0; k0 < 4; ++k0) {
    short8 ah = *(const short8*)(ab + (k0 * 3 + 0) * 512);
    short8 am = *(const short8*)(ab + (k0 * 3 + 1) * 512);
    short8 al = *(const short8*)(ab + (k0 * 3 + 2) * 512);
#pragma unroll
    for (int c = 0; c < 8; ++c) {
      const short* bp = bb + (size_t)(c * 6144 + k0 * 1536);
      short8 bh = *(const short8*)(bp);
      short8 bm = *(const short8*)(bp + 512);
      short8 bl = *(const short8*)(bp + 1024);
      acc[c] = __builtin_amdgcn_mfma_f32_16x16x32_bf16(ah, bh, acc[c], 0, 0, 0);
      acc[c] = __builtin_amdgcn_mfma_f32_16x16x32_bf16(am, bh, acc[c], 0, 0, 0);
      acc[c] = __builtin_amdgcn_mfma_f32_16x16x32_bf16(ah, bm, acc[c], 0, 0, 0);
      acc[c] = __builtin_amdgcn_mfma_f32_16x16x32_bf16(am, bm, acc[c], 0, 0, 0);
      acc[c] = __builtin_amdgcn_mfma_f32_16x16x32_bf16(al, bh, acc[c], 0, 0, 0);
      acc[c] = __builtin_amdgcn_mfma_f32_16x16x32_bf16(ah, bl, acc[c], 0, 0, 0);
    }
  }
  const float rs = 0.08838834764831845f;  // 1/sqrt(128)
  const float NEGINF = -__builtin_inff();
  int q = l >> 4, cl = l & 15;            // C/D layout: col=lane&15, row=(lane>>4)*4+reg
  int lr = l >> 3, lc = l & 7;            // read-back role: 2 rows (lr, lr+8), 4 cols/phase
  size_t brow = (size_t)b * GG;
  float e[8][4];                          // [phase*2 + iter][4 cols] - static indexing
  float rs0 = 0.f, rs1 = 0.f;             // row partials for rows lr and lr+8
  // 4 phases: stage 2 c-frags (32 cols) -> wave-private read-back, exp, partial sums
#pragma unroll
  for (int p = 0; p < 4; ++p) {
#pragma unroll
    for (int cc = 0; cc < 2; ++cc)
#pragma unroll
      for (int r = 0; r < 4; ++r)
        xs[wv][q * 4 + r][cc * 16 + cl] = acc[p * 2 + cc][r];
    // wave-private: LDS ops in-order within a wave, no barrier needed
#pragma unroll
    for (int i = 0; i < 2; ++i) {
      int row = i * 8 + lr;
      int g = gy * 32 + wg * 16 + row;
      bool gv = (g < GG);
      size_t roff = (brow + (gv ? g : GG - 1)) * (size_t)NN;
      int n0 = wn * 128 + p * 32 + lc * 4;
      bool nv = (n0 < NN);
      f32x4 v = *(const f32x4*)&xs[wv][row][lc * 4];
      float4 mvv;
      if (gv && nv) mvv = *(const float4*)(mask + roff + n0);
      else mvv = make_float4(NEGINF, NEGINF, NEGINF, NEGINF);
      float mva[4] = {mvv.x, mvv.y, mvv.z, mvv.w};
      float esum = 0.f;
#pragma unroll
      for (int j = 0; j < 4; ++j) {
        float sc = v[j] * rs;
        float u = __expf(2.f * sc);
        float th = 1.f - 2.f * __builtin_amdgcn_rcpf(u + 1.f);
        float ev = __expf(10.f * th + mva[j]);  // invalid/masked -> 0
        e[p * 2 + i][j] = ev;
        esum += ev;
      }
      if (i == 0) rs0 += esum; else rs1 += esum;
    }
  }
  // reduce row partials across the 8 lanes (lc) sharing each row
#pragma unroll
  for (int off = 1; off < 8; off <<= 1) {
    rs0 += __shfl_xor(rs0, off);
    rs1 += __shfl_xor(rs1, off);
  }
  if (lc == 0) {
    psum[wg * 16 + lr][wn] = rs0;
    psum[wg * 16 + 8 + lr][wn] = rs1;
  }
  __syncthreads();
  if (threadIdx.x < 32) {
    int t = threadIdx.x;
    float s = 0.f;
#pragma unroll
    for (int j = 0; j < 8; ++j) s += psum[t][j];
    sinv[t] = 1.f / s;
  }
  __syncthreads();
  // scale by 1/rowsum and store normalized probs (coalesced float4)
#pragma unroll
  for (int p = 0; p < 4; ++p)
#pragma unroll
    for (int i = 0; i < 2; ++i) {
      int row = i * 8 + lr;
      int g = gy * 32 + wg * 16 + row;
      int n0 = wn * 128 + p * 32 + lc * 4;
      if (g < GG && n0 < NN) {
        float inv = sinv[wg * 16 + row];
        size_t roff = (brow + g) * (size_t)NN;
        *(float4*)(out + roff + n0) = make_float4(e[p * 2 + i][0] * inv, e[p * 2 + i][1] * inv,
                                                  e[p * 2 + i][2] * inv, e[p * 2 + i][3] * inv);
      }
    }
}

extern "C" void kernel_launch(void* const* d_in, const int* in_sizes, int n_in,
                              void* d_out, int out_size, void* d_ws, size_t ws_size,
                              hipStream_t stream) {
  const int*   last_node = (const int*)d_in[0];
  const float* coords    = (const float*)d_in[1];
  const float* emb       = (const float*)d_in[2];
  const float* mask      = (const float*)d_in[3];
  const float* Wqg       = (const float*)d_in[4];
  const float* Wqf       = (const float*)d_in[5];
  const float* Wql       = (const float*)d_in[6];
  const float* Wk        = (const float*)d_in[7];
  const float* Wv        = (const float*)d_in[8];
  const float* Wc        = (const float*)d_in[9];
  const float* bc        = (const float*)d_in[10];
  float* out = (float*)d_out;
  float* ws  = (float*)d_ws;

  float* qg    = ws + OFF_QG;
  float* Karr  = ws + OFF_K;
  float* Varr  = ws + OFF_V;
  float* QFL   = ws + OFF_QFL;
  float* outg  = ws + OFF_OUTG;
  float* gpart = ws + OFF_GPART;
  short* emb3  = (short*)(ws + OFF_K);    // aliases Karr/Varr (dead after k_glimpse)
  short* fq3   = (short*)(ws + OFF_FQ);   // written by k_comb

  k_gq1<<<dim3(BD, 25), dim3(256), 0, stream>>>(emb, gpart);
  k_gq2<<<dim3(BD), dim3(128), 0, stream>>>(gpart, Wqg, qg);
  k_proj<<<dim3(125, 6), dim3(256), 0, stream>>>(emb, Wk, Wv, Wqf, Wql, Karr, Varr, QFL);
  k_glimpse<<<dim3(2000), dim3(256), 0, stream>>>(last_node, coords, mask, qg, QFL, Karr, Varr, outg);
  k_comb<<<dim3(125), dim3(256), 0, stream>>>(outg, Wc, bc, fq3);
  k_cvt<<<dim3(64, BD), dim3(256), 0, stream>>>(emb, emb3);
  k_score<<<dim3(32, BD), dim3(1024), 0, stream>>>(fq3, emb3, mask, out);
}

// Round 12
// 193.381 us; speedup vs baseline: 1.0875x; 1.0115x over previous
//
#include <hip/hip_runtime.h>
#include <math.h>

#define BD 8
#define NN 1000
#define GG 1000
#define EE 128

typedef unsigned long long u64;
typedef __attribute__((ext_vector_type(8))) short short8;   // 8 bf16 (4 VGPRs)
typedef __attribute__((ext_vector_type(4))) float f32x4;

// ws layout (floats). fq3/emb3 are SHORT buffers of 8*393216 shorts = 1,572,864
// float-slots each — slots sized accordingly (round-11 bug: fq3 slot was 1,024,000
// and overran into emb3).
#define OFF_QG    0                        // 1024
#define OFF_K     1024                     // 1,024,000
#define OFF_V     (OFF_K + 1024000)
#define OFF_QFL   (OFF_V + 1024000)
#define OFF_OUTG  (OFF_QFL + 1024000)
#define OFF_FQ    (OFF_OUTG + 1024000)     // fq3 shorts: 1,572,864 float slots
#define OFF_GPART (OFF_FQ + 1572864)       // 8*25*128 = 25,600
#define OFF_EMB3  (OFF_GPART + 25600)      // emb3 shorts: 1,572,864 float slots
#define OFF_W3    (OFF_EMB3 + 1572864)     // w3 shorts: 73,728 float slots
// high-water ~9.4M floats ~= 37.5 MB << 268 MB ws.

// ---------------- K1a: partial row sums of embeddings (B x 25 x 128) ----------------
__global__ __launch_bounds__(256) void k_gq1(const float* __restrict__ emb,
                                             float* __restrict__ gpart) {
  __shared__ float ps[2][128];
  int b = blockIdx.x, blk = blockIdx.y;
  int t = threadIdx.x;
  int e = t & 127, p = t >> 7;
  const float* eb = emb + ((size_t)b * NN + blk * 40 + p * 20) * EE + e;
  float s = 0.f;
#pragma unroll 4
  for (int n = 0; n < 20; ++n) s += eb[(size_t)n * EE];
  ps[p][e] = s;
  __syncthreads();
  if (t < 128) gpart[(b * 25 + blk) * 128 + t] = ps[0][t] + ps[1][t];
}

// ---------------- K1b: finalize mean + q_graph = mean @ Wqg^T ----------------
__global__ __launch_bounds__(128) void k_gq2(const float* __restrict__ gpart,
                                             const float* __restrict__ Wqg,
                                             float* __restrict__ qg) {
  __shared__ float ge[128];
  int b = blockIdx.x, t = threadIdx.x;
  float s = 0.f;
#pragma unroll 5
  for (int j = 0; j < 25; ++j) s += gpart[(b * 25 + j) * 128 + t];
  ge[t] = s * (1.f / 1000.f);
  __syncthreads();
  const float* wr = Wqg + (size_t)t * EE;
  float acc = 0.f;
#pragma unroll 8
  for (int k = 0; k < 128; ++k) acc += ge[k] * wr[k];
  qg[b * EE + t] = acc;
}

// ---------------- K_cvt: f32 rows -> 3-plane bf16 MFMA-fragment layout ----------------
__global__ __launch_bounds__(256) void k_cvt(const float* __restrict__ src,
                                             short* __restrict__ dst) {
  int t = blockIdx.x, b = blockIdx.y;
  int w = threadIdx.x >> 6, l = threadIdx.x & 63;
  int r = min(t * 16 + (l & 15), NN - 1);
  int k = w * 32 + (l >> 4) * 8;
  const float* sp = src + ((size_t)b * NN + r) * EE + k;
  float4 v0 = *(const float4*)sp;
  float4 v1 = *(const float4*)(sp + 4);
  float x[8] = {v0.x, v0.y, v0.z, v0.w, v1.x, v1.y, v1.z, v1.w};
  short8 hv, mv, lv;
#pragma unroll
  for (int j = 0; j < 8; ++j) {
    float xv = x[j];
    unsigned uh = __float_as_uint(xv) & 0xFFFF0000u;
    hv[j] = (short)(uh >> 16);
    float r1 = xv - __uint_as_float(uh);
    unsigned um = __float_as_uint(r1) & 0xFFFF0000u;
    mv[j] = (short)(um >> 16);
    float r2 = r1 - __uint_as_float(um);
    lv[j] = (short)(__float_as_uint(r2) >> 16);
  }
  short* dbase = dst + ((size_t)b * 393216 + (size_t)((t * 4 + w) * 3) * 512 + l * 8);
  *(short8*)(dbase)        = hv;
  *(short8*)(dbase + 512)  = mv;
  *(short8*)(dbase + 1024) = lv;
}

// ---------------- K_wcvt: [Wk;Wv;Wqf+Wql] (384x128) -> 3-plane fragments ----------------
__global__ __launch_bounds__(256) void k_wcvt(const float* __restrict__ Wk,
                                              const float* __restrict__ Wv,
                                              const float* __restrict__ Wqf,
                                              const float* __restrict__ Wql,
                                              short* __restrict__ w3) {
  int t = blockIdx.x;
  int w = threadIdx.x >> 6, l = threadIdx.x & 63;
  int j = (t >> 3) * 128 + (t & 7) * 16 + (l & 15);   // global W row 0..383
  int k = w * 32 + (l >> 4) * 8;
  float x[8];
  if (j < 128) {
    const float4* p = (const float4*)(Wk + (size_t)j * EE + k);
    float4 a = p[0], c = p[1];
    x[0] = a.x; x[1] = a.y; x[2] = a.z; x[3] = a.w;
    x[4] = c.x; x[5] = c.y; x[6] = c.z; x[7] = c.w;
  } else if (j < 256) {
    const float4* p = (const float4*)(Wv + (size_t)(j - 128) * EE + k);
    float4 a = p[0], c = p[1];
    x[0] = a.x; x[1] = a.y; x[2] = a.z; x[3] = a.w;
    x[4] = c.x; x[5] = c.y; x[6] = c.z; x[7] = c.w;
  } else {
    const float4* pf = (const float4*)(Wqf + (size_t)(j - 256) * EE + k);
    const float4* pl = (const float4*)(Wql + (size_t)(j - 256) * EE + k);
    float4 a = pf[0], c = pf[1], d = pl[0], e = pl[1];
    x[0] = a.x + d.x; x[1] = a.y + d.y; x[2] = a.z + d.z; x[3] = a.w + d.w;
    x[4] = c.x + e.x; x[5] = c.y + e.y; x[6] = c.z + e.z; x[7] = c.w + e.w;
  }
  short8 hv, mv, lv;
#pragma unroll
  for (int q = 0; q < 8; ++q) {
    float xv = x[q];
    unsigned uh = __float_as_uint(xv) & 0xFFFF0000u;
    hv[q] = (short)(uh >> 16);
    float r1 = xv - __uint_as_float(uh);
    unsigned um = __float_as_uint(r1) & 0xFFFF0000u;
    mv[q] = (short)(um >> 16);
    float r2 = r1 - __uint_as_float(um);
    lv[q] = (short)(__float_as_uint(r2) >> 16);
  }
  short* dbase = w3 + ((size_t)((t * 4 + w) * 3) * 512 + l * 8);
  *(short8*)(dbase)        = hv;
  *(short8*)(dbase + 512)  = mv;
  *(short8*)(dbase + 1024) = lv;
}

// ---------------- K2: projection GEMM on MFMA: [K|V|QFL] = emb @ W^T ----------------
__global__ __launch_bounds__(256, 2) void k_proj(const short* __restrict__ emb3,
                                                 const short* __restrict__ w3,
                                                 float* __restrict__ Karr,
                                                 float* __restrict__ Varr,
                                                 float* __restrict__ QFL) {
  __shared__ float xs[4][16][132];
  int bt = blockIdx.x, nt = blockIdx.y, b = blockIdx.z;
  int w = threadIdx.x >> 6, l = threadIdx.x & 63;
  int at = bt * 4 + w;                 // A-tile 0..63 (63 = clamped rows, stores guarded)
  const short* ab = emb3 + ((size_t)b * 393216 + (size_t)at * 6144 + l * 8);
  const short* bb = w3 + ((size_t)nt * 8 * 6144 + l * 8);
  f32x4 acc[8] = {};
#pragma unroll
  for (int k0 = 0; k0 < 4; ++k0) {
    short8 ah = *(const short8*)(ab + (k0 * 3 + 0) * 512);
    short8 am = *(const short8*)(ab + (k0 * 3 + 1) * 512);
    short8 al = *(const short8*)(ab + (k0 * 3 + 2) * 512);
#pragma unroll
    for (int c = 0; c < 8; ++c) {
      const short* bp = bb + (size_t)(c * 6144 + k0 * 1536);
      short8 bh = *(const short8*)(bp);
      short8 bm = *(const short8*)(bp + 512);
      short8 bl = *(const short8*)(bp + 1024);
      acc[c] = __builtin_amdgcn_mfma_f32_16x16x32_bf16(ah, bh, acc[c], 0, 0, 0);
      acc[c] = __builtin_amdgcn_mfma_f32_16x16x32_bf16(am, bh, acc[c], 0, 0, 0);
      acc[c] = __builtin_amdgcn_mfma_f32_16x16x32_bf16(ah, bm, acc[c], 0, 0, 0);
      acc[c] = __builtin_amdgcn_mfma_f32_16x16x32_bf16(am, bm, acc[c], 0, 0, 0);
      acc[c] = __builtin_amdgcn_mfma_f32_16x16x32_bf16(al, bh, acc[c], 0, 0, 0);
      acc[c] = __builtin_amdgcn_mfma_f32_16x16x32_bf16(ah, bl, acc[c], 0, 0, 0);
    }
  }
  int q = l >> 4, cl = l & 15;         // C/D: col=lane&15, row=(lane>>4)*4+reg
#pragma unroll
  for (int c = 0; c < 8; ++c)
#pragma unroll
    for (int r = 0; r < 4; ++r)
      xs[w][q * 4 + r][c * 16 + cl] = acc[c][r];
  float* dest = (nt == 0 ? Karr : nt == 1 ? Varr : QFL) + (size_t)b * NN * EE;
  int half = l >> 5, ln = l & 31;
#pragma unroll
  for (int it = 0; it < 8; ++it) {
    int row = it * 2 + half;
    int g = at * 16 + row;
    if (g < NN) {
      f32x4 v = *(const f32x4*)&xs[w][row][ln * 4];
      *(float4*)(dest + (size_t)g * EE + ln * 4) = make_float4(v[0], v[1], v[2], v[3]);
    }
  }
}

// ----- u32 wave-min helpers (DPP row rotations + shfl for 16/32) -----
template <int CTRL>
__device__ __forceinline__ unsigned dpp_minu(unsigned x) {
  unsigned o = (unsigned)__builtin_amdgcn_update_dpp(0, (int)x, CTRL, 0xf, 0xf, false);
  return o < x ? o : x;
}
__device__ __forceinline__ unsigned wave_min_u32(unsigned x) {
  x = dpp_minu<0x121>(x);
  x = dpp_minu<0x122>(x);
  x = dpp_minu<0x124>(x);
  x = dpp_minu<0x128>(x);
  unsigned o = (unsigned)__shfl_xor((int)x, 16); x = o < x ? o : x;
  o = (unsigned)__shfl_xor((int)x, 32); x = o < x ? o : x;
  return x;
}

// ---------------- K3: per-(b,g) KNN + glimpse attention -> outg (B,G,128) ----------------
__global__ __launch_bounds__(256) void k_glimpse(const int* __restrict__ last_node,
                                                 const float* __restrict__ coords,
                                                 const float* __restrict__ mask,
                                                 const float* __restrict__ qg,
                                                 const float* __restrict__ QFL,
                                                 const float* __restrict__ Karr,
                                                 const float* __restrict__ Varr,
                                                 float* __restrict__ outg) {
  __shared__ float pbuf[4][128];
  __shared__ int   nbuf[4][16];
  const float INF = __builtin_inff();
  int wv = threadIdx.x >> 6;
  int lane = threadIdx.x & 63;
  int wid = (blockIdx.x * blockDim.x + threadIdx.x) >> 6;
  int b = wid / GG, g = wid % GG;
  int last = last_node[b * GG + g];
  const float2* cb2 = (const float2*)(coords + (size_t)b * NN * 2);
  float2 lc = cb2[last];
  float lc2 = lc.x * lc.x + lc.y * lc.y;
  const float* mrow = mask + ((size_t)b * GG + g) * NN;
  unsigned d2u[16];
#pragma unroll
  for (int i = 0; i < 16; ++i) {
    int n = lane + (i << 6);
    unsigned k = 0xFFFFFFFFu;
    if (n < NN) {
      float2 c = cb2[n];
      float d2 = lc2 + (c.x * c.x + c.y * c.y) - 2.f * (lc.x * c.x + lc.y * c.y);
      d2 = fmaxf(d2, 0.f);
      k = __float_as_uint(d2);
      if (mrow[n] == -INF) k = 0x7F800000u;
    }
    d2u[i] = k;
  }
  int h = lane >> 3;
  int kk = lane & 7;
  int n0sel = 0, n1sel = 0;
  for (int s = 0; s < 16; ++s) {
    unsigned bv = d2u[0]; int bs = 0;
#pragma unroll
    for (int i = 1; i < 16; ++i) {
      bool better = d2u[i] < bv;
      bv = better ? d2u[i] : bv;
      bs = better ? i : bs;
    }
    unsigned wm = wave_min_u32(bv);
    u64 tied = __ballot(bv == wm);
    int wn;
    if (__popcll(tied) == 1) {
      int wl = (int)__builtin_ctzll(tied);
      int ws = __builtin_amdgcn_readlane(bs, wl);
      wn = wl + (ws << 6);
    } else {
      unsigned cn = (bv == wm) ? (unsigned)(lane + (bs << 6)) : 0x7FFFFFFFu;
      cn = wave_min_u32(cn);
      wn = (int)__builtin_amdgcn_readfirstlane((int)cn);
    }
    n0sel = (s == kk) ? wn : n0sel;
    n1sel = (s == kk + 8) ? wn : n1sel;
    int iw = wn >> 6;
    bool me = (lane == (wn & 63));
#pragma unroll
    for (int i = 0; i < 16; ++i)
      if (i == iw && me) d2u[i] = 0xFFFFFFFFu;
  }
  float qh[16];
  {
    const float4* qg4 = (const float4*)(qg + b * EE + h * 16);
    const float4* qf4 = (const float4*)(QFL + ((size_t)b * NN + last) * EE + h * 16);
#pragma unroll
    for (int u = 0; u < 4; ++u) {
      float4 a = qg4[u], c = qf4[u];
      qh[u * 4 + 0] = a.x + c.x; qh[u * 4 + 1] = a.y + c.y;
      qh[u * 4 + 2] = a.z + c.z; qh[u * 4 + 3] = a.w + c.w;
    }
  }
  const float* Kb = Karr + (size_t)b * NN * EE;
  float s0 = 0.f, s1 = 0.f;
  {
    const float4* k04 = (const float4*)(Kb + (size_t)n0sel * EE + h * 16);
    const float4* k14 = (const float4*)(Kb + (size_t)n1sel * EE + h * 16);
    float4 ka[4], kb[4];
#pragma unroll
    for (int u = 0; u < 4; ++u) { ka[u] = k04[u]; kb[u] = k14[u]; }
#pragma unroll
    for (int u = 0; u < 4; ++u) {
      s0 += qh[u * 4 + 0] * ka[u].x; s0 += qh[u * 4 + 1] * ka[u].y;
      s0 += qh[u * 4 + 2] * ka[u].z; s0 += qh[u * 4 + 3] * ka[u].w;
      s1 += qh[u * 4 + 0] * kb[u].x; s1 += qh[u * 4 + 1] * kb[u].y;
      s1 += qh[u * 4 + 2] * kb[u].z; s1 += qh[u * 4 + 3] * kb[u].w;
    }
  }
  s0 *= 0.25f; s1 *= 0.25f;
  float m = fmaxf(s0, s1);
#pragma unroll
  for (int off = 1; off < 8; off <<= 1) m = fmaxf(m, __shfl_xor(m, off));
  float e0 = __expf(s0 - m), e1 = __expf(s1 - m);
  float se = e0 + e1;
#pragma unroll
  for (int off = 1; off < 8; off <<= 1) se += __shfl_xor(se, off);
  float p0 = e0 / se, p1 = e1 / se;
  pbuf[wv][h * 16 + kk] = p0;
  pbuf[wv][h * 16 + kk + 8] = p1;
  if (h == 0) { nbuf[wv][kk] = n0sel; nbuf[wv][kk + 8] = n1sel; }
  const float* Vb = Varr + (size_t)b * NN * EE;
  float o0 = 0.f, o1 = 0.f;
#pragma unroll
  for (int c = 0; c < 2; ++c) {
    int nk[8]; float pk[8]; float2 vv[8];
#pragma unroll
    for (int j = 0; j < 8; ++j) { nk[j] = nbuf[wv][c * 8 + j]; pk[j] = pbuf[wv][h * 16 + c * 8 + j]; }
#pragma unroll
    for (int j = 0; j < 8; ++j)
      vv[j] = *(const float2*)(Vb + (size_t)nk[j] * EE + h * 16 + kk * 2);
#pragma unroll
    for (int j = 0; j < 8; ++j) { o0 += pk[j] * vv[j].x; o1 += pk[j] * vv[j].y; }
  }
  *(float2*)(outg + ((size_t)b * GG + g) * EE + h * 16 + kk * 2) = make_float2(o0, o1);
}

// ---------------- K4: final_q = outg @ W_comb^T + b_comb -> fq3 fragments directly ------
__global__ __launch_bounds__(256) void k_comb(const float* __restrict__ outg,
                                              const float* __restrict__ Wc,
                                              const float* __restrict__ bc,
                                              short* __restrict__ fq3) {
  __shared__ float Als[16][68];
  __shared__ float Bls[16][132];
  int mt = blockIdx.x;
  int t = threadIdx.x;
  int ty = t >> 4, tx = t & 15;
  int la = t >> 2, akq = t & 3;
  int lb = t >> 1, bkq = t & 1;
  const float* apos = outg + (size_t)(mt * 64 + la) * EE + akq * 4;
  const float* bpos = Wc + (size_t)lb * EE + bkq * 8;
  float acc[4][8] = {};
  float4 pa  = *(const float4*)apos;
  float4 pb0 = *(const float4*)bpos;
  float4 pb1 = *(const float4*)(bpos + 4);
  for (int k0 = 0; k0 < 128; k0 += 16) {
    __syncthreads();
    Als[akq * 4 + 0][la] = pa.x;  Als[akq * 4 + 1][la] = pa.y;
    Als[akq * 4 + 2][la] = pa.z;  Als[akq * 4 + 3][la] = pa.w;
    Bls[bkq * 8 + 0][lb] = pb0.x; Bls[bkq * 8 + 1][lb] = pb0.y;
    Bls[bkq * 8 + 2][lb] = pb0.z; Bls[bkq * 8 + 3][lb] = pb0.w;
    Bls[bkq * 8 + 4][lb] = pb1.x; Bls[bkq * 8 + 5][lb] = pb1.y;
    Bls[bkq * 8 + 6][lb] = pb1.z; Bls[bkq * 8 + 7][lb] = pb1.w;
    __syncthreads();
    if (k0 < 112) {
      pa  = *(const float4*)(apos + k0 + 16);
      pb0 = *(const float4*)(bpos + k0 + 16);
      pb1 = *(const float4*)(bpos + k0 + 20);
    }
#pragma unroll
    for (int k = 0; k < 16; ++k) {
      float4 av  = *(const float4*)&Als[k][ty * 4];
      float4 bv0 = *(const float4*)&Bls[k][tx * 8];
      float4 bv1 = *(const float4*)&Bls[k][tx * 8 + 4];
      float af[4] = {av.x, av.y, av.z, av.w};
      float bf[8] = {bv0.x, bv0.y, bv0.z, bv0.w, bv1.x, bv1.y, bv1.z, bv1.w};
#pragma unroll
      for (int i = 0; i < 4; ++i)
#pragma unroll
        for (int j = 0; j < 8; ++j) acc[i][j] += af[i] * bf[j];
    }
  }
  int c0 = tx * 8;
  float4 b0 = *(const float4*)(bc + c0);
  float4 b1 = *(const float4*)(bc + c0 + 4);
  float bias[8] = {b0.x, b0.y, b0.z, b0.w, b1.x, b1.y, b1.z, b1.w};
  int k0f = tx >> 2;
  int lsub = tx & 3;
#pragma unroll
  for (int i = 0; i < 4; ++i) {
    int r = mt * 64 + ty * 4 + i;
    int b = r / GG;
    int g = r - b * GG;
    short8 hv, mv, lv;
#pragma unroll
    for (int j = 0; j < 8; ++j) {
      float xv = acc[i][j] + bias[j];
      unsigned uh = __float_as_uint(xv) & 0xFFFF0000u;
      hv[j] = (short)(uh >> 16);
      float r1 = xv - __uint_as_float(uh);
      unsigned um = __float_as_uint(r1) & 0xFFFF0000u;
      mv[j] = (short)(um >> 16);
      float r2 = r1 - __uint_as_float(um);
      lv[j] = (short)(__float_as_uint(r2) >> 16);
    }
    int tile = g >> 4;
    int lanefrag = (g & 15) + lsub * 16;
    short* dbase = fq3 + ((size_t)b * 393216 + (size_t)((tile * 4 + k0f) * 3) * 512 + lanefrag * 8);
    *(short8*)(dbase)        = hv;
    *(short8*)(dbase + 512)  = mv;
    *(short8*)(dbase + 1024) = lv;
  }
}

// ---------------- K5: score GEMM (split-bf16 MFMA) + tanh/exp + FUSED row-normalize -----
__global__ __launch_bounds__(1024, 1) void k_score(const short* __restrict__ fq3,
                                                   const short* __restrict__ emb3,
                                                   const float* __restrict__ mask,
                                                   float* __restrict__ out) {
  __shared__ float xs[16][16][36];
  __shared__ float psum[32][8];
  __shared__ float sinv[32];
  int gy = blockIdx.x, b = blockIdx.y;
  int wv = threadIdx.x >> 6, l = threadIdx.x & 63;
  int wg = wv >> 3, wn = wv & 7;
  int gtile = gy * 2 + wg;
  const short* ab = fq3 + ((size_t)b * 393216 + (size_t)gtile * 6144 + l * 8);
  const short* bb = emb3 + ((size_t)b * 393216 + (size_t)wn * 8 * 6144 + l * 8);
  f32x4 acc[8] = {};
#pragma unroll
  for (int k0 = 0; k0 < 4; ++k0) {
    short8 ah = *(const short8*)(ab + (k0 * 3 + 0) * 512);
    short8 am = *(const short8*)(ab + (k0 * 3 + 1) * 512);
    short8 al = *(const short8*)(ab + (k0 * 3 + 2) * 512);
#pragma unroll
    for (int c = 0; c < 8; ++c) {
      const short* bp = bb + (size_t)(c * 6144 + k0 * 1536);
      short8 bh = *(const short8*)(bp);
      short8 bm = *(const short8*)(bp + 512);
      short8 bl = *(const short8*)(bp + 1024);
      acc[c] = __builtin_amdgcn_mfma_f32_16x16x32_bf16(ah, bh, acc[c], 0, 0, 0);
      acc[c] = __builtin_amdgcn_mfma_f32_16x16x32_bf16(am, bh, acc[c], 0, 0, 0);
      acc[c] = __builtin_amdgcn_mfma_f32_16x16x32_bf16(ah, bm, acc[c], 0, 0, 0);
      acc[c] = __builtin_amdgcn_mfma_f32_16x16x32_bf16(am, bm, acc[c], 0, 0, 0);
      acc[c] = __builtin_amdgcn_mfma_f32_16x16x32_bf16(al, bh, acc[c], 0, 0, 0);
      acc[c] = __builtin_amdgcn_mfma_f32_16x16x32_bf16(ah, bl, acc[c], 0, 0, 0);
    }
  }
  const float rs = 0.08838834764831845f;
  const float NEGINF = -__builtin_inff();
  int q = l >> 4, cl = l & 15;
  int lr = l >> 3, lc = l & 7;
  size_t brow = (size_t)b * GG;
  float e[8][4];
  float rs0 = 0.f, rs1 = 0.f;
#pragma unroll
  for (int p = 0; p < 4; ++p) {
#pragma unroll
    for (int cc = 0; cc < 2; ++cc)
#pragma unroll
      for (int r = 0; r < 4; ++r)
        xs[wv][q * 4 + r][cc * 16 + cl] = acc[p * 2 + cc][r];
#pragma unroll
    for (int i = 0; i < 2; ++i) {
      int row = i * 8 + lr;
      int g = gy * 32 + wg * 16 + row;
      bool gv = (g < GG);
      size_t roff = (brow + (gv ? g : GG - 1)) * (size_t)NN;
      int n0 = wn * 128 + p * 32 + lc * 4;
      bool nv = (n0 < NN);
      f32x4 v = *(const f32x4*)&xs[wv][row][lc * 4];
      float4 mvv;
      if (gv && nv) mvv = *(const float4*)(mask + roff + n0);
      else mvv = make_float4(NEGINF, NEGINF, NEGINF, NEGINF);
      float mva[4] = {mvv.x, mvv.y, mvv.z, mvv.w};
      float esum = 0.f;
#pragma unroll
      for (int j = 0; j < 4; ++j) {
        float sc = v[j] * rs;
        float u = __expf(2.f * sc);
        float th = 1.f - 2.f * __builtin_amdgcn_rcpf(u + 1.f);
        float ev = __expf(10.f * th + mva[j]);
        e[p * 2 + i][j] = ev;
        esum += ev;
      }
      if (i == 0) rs0 += esum; else rs1 += esum;
    }
  }
#pragma unroll
  for (int off = 1; off < 8; off <<= 1) {
    rs0 += __shfl_xor(rs0, off);
    rs1 += __shfl_xor(rs1, off);
  }
  if (lc == 0) {
    psum[wg * 16 + lr][wn] = rs0;
    psum[wg * 16 + 8 + lr][wn] = rs1;
  }
  __syncthreads();
  if (threadIdx.x < 32) {
    int t = threadIdx.x;
    float s = 0.f;
#pragma unroll
    for (int j = 0; j < 8; ++j) s += psum[t][j];
    sinv[t] = 1.f / s;
  }
  __syncthreads();
#pragma unroll
  for (int p = 0; p < 4; ++p)
#pragma unroll
    for (int i = 0; i < 2; ++i) {
      int row = i * 8 + lr;
      int g = gy * 32 + wg * 16 + row;
      int n0 = wn * 128 + p * 32 + lc * 4;
      if (g < GG && n0 < NN) {
        float inv = sinv[wg * 16 + row];
        size_t roff = (brow + g) * (size_t)NN;
        *(float4*)(out + roff + n0) = make_float4(e[p * 2 + i][0] * inv, e[p * 2 + i][1] * inv,
                                                  e[p * 2 + i][2] * inv, e[p * 2 + i][3] * inv);
      }
    }
}

extern "C" void kernel_launch(void* const* d_in, const int* in_sizes, int n_in,
                              void* d_out, int out_size, void* d_ws, size_t ws_size,
                              hipStream_t stream) {
  const int*   last_node = (const int*)d_in[0];
  const float* coords    = (const float*)d_in[1];
  const float* emb       = (const float*)d_in[2];
  const float* mask      = (const float*)d_in[3];
  const float* Wqg       = (const float*)d_in[4];
  const float* Wqf       = (const float*)d_in[5];
  const float* Wql       = (const float*)d_in[6];
  const float* Wk        = (const float*)d_in[7];
  const float* Wv        = (const float*)d_in[8];
  const float* Wc        = (const float*)d_in[9];
  const float* bc        = (const float*)d_in[10];
  float* out = (float*)d_out;
  float* ws  = (float*)d_ws;

  float* qg    = ws + OFF_QG;
  float* Karr  = ws + OFF_K;
  float* Varr  = ws + OFF_V;
  float* QFL   = ws + OFF_QFL;
  float* outg  = ws + OFF_OUTG;
  float* gpart = ws + OFF_GPART;
  short* fq3   = (short*)(ws + OFF_FQ);
  short* emb3  = (short*)(ws + OFF_EMB3);
  short* w3    = (short*)(ws + OFF_W3);

  k_cvt<<<dim3(64, BD), dim3(256), 0, stream>>>(emb, emb3);
  k_wcvt<<<dim3(24), dim3(256), 0, stream>>>(Wk, Wv, Wqf, Wql, w3);
  k_gq1<<<dim3(BD, 25), dim3(256), 0, stream>>>(emb, gpart);
  k_gq2<<<dim3(BD), dim3(128), 0, stream>>>(gpart, Wqg, qg);
  k_proj<<<dim3(16, 3, BD), dim3(256), 0, stream>>>(emb3, w3, Karr, Varr, QFL);
  k_glimpse<<<dim3(2000), dim3(256), 0, stream>>>(last_node, coords, mask, qg, QFL, Karr, Varr, outg);
  k_comb<<<dim3(125), dim3(256), 0, stream>>>(outg, Wc, bc, fq3);
  k_score<<<dim3(32, BD), dim3(1024), 0, stream>>>(fq3, emb3, mask, out);
}